// Round 1
// baseline (587.277 us; speedup 1.0000x reference)
//
#include <hip/hip_runtime.h>
#include <hip/hip_bf16.h>
#include <math.h>

// Problem constants
#define BB 16
#define NN 400
#define TT 12
#define CIN 2
#define HID 256
#define HH 8
#define DD 32
#define PP 3
#define LL 3600
#define NODES (BB*NN)   // 6400

// ---------------- helpers ----------------
__device__ __forceinline__ float block_reduce_sum(float v, float* red) {
    int tid = threadIdx.x;
    red[tid] = v; __syncthreads();
    for (int s = 128; s > 0; s >>= 1) {
        if (tid < s) red[tid] += red[tid + s];
        __syncthreads();
    }
    float r = red[0];
    __syncthreads();
    return r;
}

// ---------------- weight prep ----------------
// Wcat1[(tt*256+i)][which*256+o] = w_which1[o][i][tt]   (768 x 768)
__global__ __launch_bounds__(256) void build_wcat1(
    const float* __restrict__ wg1, const float* __restrict__ wf1,
    const float* __restrict__ ws1, float* __restrict__ W) {
    int idx = blockIdx.x * 256 + threadIdx.x;
    if (idx >= 768 * 768) return;
    int j = idx / 768, mcol = idx % 768;
    int tt = j / 256, i = j % 256;
    int which = mcol / 256, o = mcol % 256;
    const float* w = which == 0 ? wg1 : (which == 1 ? wf1 : ws1);
    W[idx] = w[(o * 256 + i) * 3 + tt];
}

// Wcat2[c][m]  (256 x 544): [sWv | dWv | Aq(8) | Ak(8) | Bq(8) | Bk(8)]
__global__ __launch_bounds__(256) void build_wcat2(
    const float* __restrict__ sWv, const float* __restrict__ dWv,
    const float* __restrict__ sWq, const float* __restrict__ saq,
    const float* __restrict__ sWk, const float* __restrict__ sak,
    const float* __restrict__ dWq, const float* __restrict__ daq,
    const float* __restrict__ dWk, const float* __restrict__ dak,
    float* __restrict__ W) {
    int idx = blockIdx.x * 256 + threadIdx.x;
    if (idx >= 256 * 544) return;
    int cc = idx / 544, mcol = idx % 544;
    float v;
    if (mcol < 256) v = sWv[cc * 256 + mcol];
    else if (mcol < 512) v = dWv[cc * 256 + (mcol - 256)];
    else {
        int g = (mcol - 512) / 8, h = (mcol - 512) % 8;
        const float* Wm = g == 0 ? sWq : (g == 1 ? sWk : (g == 2 ? dWq : dWk));
        const float* am = g == 0 ? saq : (g == 1 ? sak : (g == 2 ? daq : dak));
        float s = 0.f;
        for (int d = 0; d < 32; d++) s += Wm[cc * 256 + h * 32 + d] * am[h * 32 + d];
        v = s;
    }
    W[idx] = v;
}

// Wcat3 (512 x 768): rows 0..255 = hf channels, 256..511 = ha channels
__global__ __launch_bounds__(256) void build_wcat3(
    const float* __restrict__ fW1, const float* __restrict__ fW2,
    const float* __restrict__ fW3, float* __restrict__ W) {
    int idx = blockIdx.x * 256 + threadIdx.x;
    if (idx >= 512 * 768) return;
    int c2 = idx / 768, mcol = idx % 768;
    float v = 0.f;
    if (c2 < 256) {
        if (mcol < 256) v = fW1[c2 * 256 + mcol];
        else if (mcol < 512) v = fW2[c2 * 256 + (mcol - 256)];
    } else {
        int cc = c2 - 256;
        if (mcol < 256) v = fW1[cc * 256 + mcol];
        else if (mcol >= 512) v = fW3[cc * 256 + (mcol - 512)];
    }
    W[idx] = v;
}

// AeS[c*8+h] = sum_d sWe[c][h*32+d]*sae[h][d]
__global__ void build_aes(const float* __restrict__ sWe,
                          const float* __restrict__ sae,
                          float* __restrict__ AeS) {
    int tid = threadIdx.x;
    if (tid < 16) {
        int cc = tid / 8, h = tid % 8;
        float s = 0.f;
        for (int d = 0; d < 32; d++) s += sWe[cc * 256 + h * 32 + d] * sae[h * 32 + d];
        AeS[tid] = s;
    }
}

// ---------------- adjacency (A = softmax(relu(E1 E2^T)), top-16 sparse) ----------------
__global__ __launch_bounds__(256) void adj_kernel(
    const float* __restrict__ E1, const float* __restrict__ E2,
    int* __restrict__ cnt, int* __restrict__ idxs, float* __restrict__ logv) {
    int n = blockIdx.x, tid = threadIdx.x;
    __shared__ float a[400];
    __shared__ float m[400];
    __shared__ float e1[10];
    __shared__ float rv[256];
    __shared__ int ri[256];
    if (tid < 10) e1[tid] = E1[n * 10 + tid];
    __syncthreads();
    for (int j = tid; j < 400; j += 256) {
        float sc = 0.f;
        for (int k = 0; k < 10; k++) sc += e1[k] * E2[j * 10 + k];
        a[j] = fmaxf(sc, 0.f);
    }
    __syncthreads();
    // row softmax
    float lm = -1e30f;
    for (int j = tid; j < 400; j += 256) lm = fmaxf(lm, a[j]);
    rv[tid] = lm; __syncthreads();
    for (int s = 128; s > 0; s >>= 1) { if (tid < s) rv[tid] = fmaxf(rv[tid], rv[tid + s]); __syncthreads(); }
    float mx = rv[0]; __syncthreads();
    float ls = 0.f;
    for (int j = tid; j < 400; j += 256) { float e = expf(a[j] - mx); a[j] = e; ls += e; }
    rv[tid] = ls; __syncthreads();
    for (int s = 128; s > 0; s >>= 1) { if (tid < s) rv[tid] += rv[tid + s]; __syncthreads(); }
    float den = rv[0]; __syncthreads();
    for (int j = tid; j < 400; j += 256) { a[j] /= den; m[j] = a[j]; }
    __syncthreads();
    // remove 15 maxima; 16th-largest = max of remainder
    for (int p = 0; p < 15; p++) {
        float bv = -1e30f; int bi = 400;
        for (int j = tid; j < 400; j += 256)
            if (m[j] > bv || (m[j] == bv && j < bi)) { bv = m[j]; bi = j; }
        rv[tid] = bv; ri[tid] = bi; __syncthreads();
        for (int s = 128; s > 0; s >>= 1) {
            if (tid < s) {
                if (rv[tid + s] > rv[tid] || (rv[tid + s] == rv[tid] && ri[tid + s] < ri[tid])) {
                    rv[tid] = rv[tid + s]; ri[tid] = ri[tid + s];
                }
            }
            __syncthreads();
        }
        if (tid == 0) m[ri[0]] = -1e30f;
        __syncthreads();
    }
    float bv = -1e30f;
    for (int j = tid; j < 400; j += 256) bv = fmaxf(bv, m[j]);
    rv[tid] = bv; __syncthreads();
    for (int s = 128; s > 0; s >>= 1) { if (tid < s) rv[tid] = fmaxf(rv[tid], rv[tid + s]); __syncthreads(); }
    float kth = rv[0]; __syncthreads();
    if (tid == 0) {
        int c = 0;
        for (int j = 0; j < 400; j++) {
            if (a[j] >= kth && c < 64) {
                idxs[n * 64 + c] = j;
                logv[n * 64 + c] = logf(fmaxf(a[j], 1e-12f));
                c++;
            }
        }
        cnt[n] = c;
    }
}

// ---------------- TCN layer 0 at t in {7,9,11} -> X (6400 x 768) ----------------
__global__ __launch_bounds__(256) void tcn0_kernel(
    const float* __restrict__ x,
    const float* __restrict__ wg0, const float* __restrict__ bg0,
    const float* __restrict__ wf0, const float* __restrict__ bf0,
    const float* __restrict__ ws0, const float* __restrict__ bs0,
    const float* __restrict__ lg, const float* __restrict__ lb,
    float* __restrict__ X) {
    int node = blockIdx.x;
    int o = threadIdx.x;
    __shared__ float xs[7][2];
    __shared__ float red[256];
    if (o < 14) { int t = 5 + o / 2, c = o & 1; xs[t - 5][c] = x[(size_t)(node * 12 + t) * 2 + c]; }
    __syncthreads();
    float wg[6], wf[6], ws[6];
    for (int i = 0; i < 6; i++) { wg[i] = wg0[o * 6 + i]; wf[i] = wf0[o * 6 + i]; ws[i] = ws0[o * 6 + i]; }
    float bg = bg0[o], bf = bf0[o], bs = bs0[o];
    float gln = lg[o], bln = lb[o];
    for (int tt = 0; tt < 3; tt++) {
        int t = 7 + 2 * tt;
        float g = bg, f = bf, s = bs;
        for (int k = 0; k < 3; k++) {
            int ti = t - 2 + k - 5;
            for (int c = 0; c < 2; c++) {
                float xv = xs[ti][c];
                g += wg[c * 3 + k] * xv;
                f += wf[c * 3 + k] * xv;
                s += ws[c * 3 + k] * xv;
            }
        }
        float gate = 1.f / (1.f + expf(-g));
        float y = gate * f + (1.f - gate) * s;
        float sum = block_reduce_sum(y, red);
        float sq = block_reduce_sum(y * y, red);
        float mean = sum * (1.f / 256.f);
        float var = sq * (1.f / 256.f) - mean * mean;
        float v = (y - mean) * rsqrtf(var + 1e-5f) * gln + bln;
        v = fmaxf(v, 0.f);
        X[(size_t)node * 768 + tt * 256 + o] = v;
    }
}

// ---------------- generic fp32 tiled GEMM: C = A(MxK) * B(KxN) ----------------
__global__ __launch_bounds__(256) void gemm_f32(
    int M, int N, int Kd,
    const float* __restrict__ A, int lda,
    const float* __restrict__ B, int ldb,
    float* __restrict__ C, int ldc) {
    __shared__ float As[16][65];
    __shared__ float Bs[16][65];
    int tid = threadIdx.x;
    int tx = tid & 15, ty = tid >> 4;
    int row0 = blockIdx.y * 64, col0 = blockIdx.x * 64;
    float acc[4][4] = {};
    for (int k0 = 0; k0 < Kd; k0 += 16) {
        #pragma unroll
        for (int i = 0; i < 4; i++) {
            int li = tid * 4 + i;
            int m = li >> 4, kk = li & 15;
            float vA = 0.f;
            int r = row0 + m, c = k0 + kk;
            if (r < M && c < Kd) vA = A[(size_t)r * lda + c];
            As[kk][m] = vA;
        }
        #pragma unroll
        for (int i = 0; i < 4; i++) {
            int li = tid * 4 + i;
            int kk = li >> 6, nn = li & 63;
            float vB = 0.f;
            int r = k0 + kk, c = col0 + nn;
            if (r < Kd && c < N) vB = B[(size_t)r * ldb + c];
            Bs[kk][nn] = vB;
        }
        __syncthreads();
        #pragma unroll
        for (int kk = 0; kk < 16; kk++) {
            float ar[4], br[4];
            #pragma unroll
            for (int i = 0; i < 4; i++) ar[i] = As[kk][ty * 4 + i];
            #pragma unroll
            for (int j = 0; j < 4; j++) br[j] = Bs[kk][tx * 4 + j];
            #pragma unroll
            for (int i = 0; i < 4; i++)
                #pragma unroll
                for (int j = 0; j < 4; j++)
                    acc[i][j] += ar[i] * br[j];
        }
        __syncthreads();
    }
    for (int i = 0; i < 4; i++) {
        int r = row0 + ty * 4 + i;
        if (r >= M) continue;
        for (int j = 0; j < 4; j++) {
            int c = col0 + tx * 4 + j;
            if (c < N) C[(size_t)r * ldc + c] = acc[i][j];
        }
    }
}

// ---------------- layer-1 epilogue: gate/LN/relu + skip -> hl ----------------
__global__ __launch_bounds__(256) void epi1_kernel(
    const float* __restrict__ Y1, const float* __restrict__ x,
    const float* __restrict__ bg1, const float* __restrict__ bf1, const float* __restrict__ bs1,
    const float* __restrict__ lg, const float* __restrict__ lb,
    const float* __restrict__ wsk, const float* __restrict__ bsk,
    float* __restrict__ hl) {
    int node = blockIdx.x, o = threadIdx.x;
    __shared__ float red[256];
    size_t base = (size_t)node * 768;
    float g = Y1[base + o] + bg1[o];
    float f = Y1[base + 256 + o] + bf1[o];
    float s = Y1[base + 512 + o] + bs1[o];
    float gate = 1.f / (1.f + expf(-g));
    float y = gate * f + (1.f - gate) * s;
    float sum = block_reduce_sum(y, red);
    float sq = block_reduce_sum(y * y, red);
    float mean = sum * (1.f / 256.f);
    float var = sq * (1.f / 256.f) - mean * mean;
    float v = (y - mean) * rsqrtf(var + 1e-5f) * lg[o] + lb[o];
    v = fmaxf(v, 0.f);
    float x0 = x[(size_t)(node * 12 + 11) * 2];
    float x1 = x[(size_t)(node * 12 + 11) * 2 + 1];
    float res = x0 * wsk[o] + x1 * wsk[256 + o] + bsk[o];
    hl[(size_t)node * 256 + o] = v + res;
}

// ---------------- fixed-graph GAT -> h_fixed (first half of U) ----------------
__global__ __launch_bounds__(256) void gat_fixed_kernel(
    const float* __restrict__ Y2, const float* __restrict__ ef,
    const int* __restrict__ fei, const float* __restrict__ AeS,
    float* __restrict__ U) {
    int node = blockIdx.x;
    int b = node / 400, n = node % 400;
    int tid = threadIdx.x;
    __shared__ int snd[9];
    __shared__ float sv[9][8];
    __shared__ float al[9][8];
    if (tid < 9) snd[tid] = fei[LL + n * 9 + tid];
    __syncthreads();
    if (tid < 72) {
        int j = tid / 8, h = tid % 8;
        int l = n * 9 + j;
        float e0 = ef[((size_t)b * LL + l) * 2];
        float e1 = ef[((size_t)b * LL + l) * 2 + 1];
        float ae = e0 * AeS[h] + e1 * AeS[8 + h];
        float aq = Y2[(size_t)node * 544 + 512 + h];
        float ak = Y2[((size_t)(b * 400 + snd[j])) * 544 + 520 + h];
        float s = aq + ak + ae;
        s = s > 0.f ? s : 0.2f * s;
        sv[j][h] = s;
    }
    __syncthreads();
    if (tid < 8) {
        int h = tid;
        float mx = -1e30f;
        for (int j = 0; j < 9; j++) mx = fmaxf(mx, sv[j][h]);
        float den = 0.f;
        for (int j = 0; j < 9; j++) { float e = expf(sv[j][h] - mx); al[j][h] = e; den += e; }
        den = fmaxf(den, 1e-12f);
        for (int j = 0; j < 9; j++) al[j][h] /= den;
    }
    __syncthreads();
    int h = tid >> 5, d = tid & 31;
    float acc = 0.f;
    for (int j = 0; j < 9; j++)
        acc += al[j][h] * Y2[((size_t)(b * 400 + snd[j])) * 544 + h * 32 + d];
    float e = acc > 0.f ? acc : (expf(acc) - 1.f);
    U[(size_t)node * 512 + tid] = e;
}

// ---------------- adaptive attention -> h_adp (second half of U) ----------------
__global__ __launch_bounds__(256) void gat_adp_kernel(
    const float* __restrict__ Y2, const int* __restrict__ cnt,
    const int* __restrict__ idxs, const float* __restrict__ logv,
    float* __restrict__ U) {
    int node = blockIdx.x;
    int b = node / 400, n = node % 400;
    int tid = threadIdx.x;
    __shared__ int jidx[64];
    __shared__ float jlog[64];
    __shared__ float sc[64][8];
    __shared__ float alb[64][8];
    int c = cnt[n];
    if (tid < c) { jidx[tid] = idxs[n * 64 + tid]; jlog[tid] = logv[n * 64 + tid]; }
    __syncthreads();
    for (int e = tid; e < c * 8; e += 256) {
        int j = e / 8, h = e % 8;
        float aq = Y2[(size_t)node * 544 + 528 + h];
        float ak = Y2[((size_t)(b * 400 + jidx[j])) * 544 + 536 + h];
        float s = aq + ak;
        s = s > 0.f ? s : 0.2f * s;
        sc[j][h] = s + jlog[j];
    }
    __syncthreads();
    if (tid < 8) {
        int h = tid; float mx = -1e30f;
        for (int j = 0; j < c; j++) mx = fmaxf(mx, sc[j][h]);
        float den = 0.f;
        for (int j = 0; j < c; j++) { float e = expf(sc[j][h] - mx); alb[j][h] = e; den += e; }
        for (int j = 0; j < c; j++) alb[j][h] /= den;
    }
    __syncthreads();
    int h = tid >> 5, d = tid & 31;
    float acc = 0.f;
    for (int j = 0; j < c; j++)
        acc += alb[j][h] * Y2[((size_t)(b * 400 + jidx[j])) * 544 + 256 + h * 32 + d];
    float e = acc > 0.f ? acc : (expf(acc) - 1.f);
    U[(size_t)node * 512 + 256 + tid] = e;
}

// ---------------- final fuse + output projection ----------------
__global__ __launch_bounds__(256) void final_kernel(
    const float* __restrict__ Y3,
    const float* __restrict__ fb1, const float* __restrict__ fb2, const float* __restrict__ fb3,
    const float* __restrict__ Wo, const float* __restrict__ bo,
    float* __restrict__ out) {
    int node = blockIdx.x, o = threadIdx.x;
    __shared__ float red[256];
    size_t base = (size_t)node * 768;
    float g = 1.f / (1.f + expf(-(Y3[base + o] + fb1[o])));
    float a2 = Y3[base + 256 + o] + fb2[o];
    float a3 = Y3[base + 512 + o] + fb3[o];
    float fused = tanhf(g * a2 + (1.f - g) * a3);
    for (int p = 0; p < 3; p++) {
        float val = fused * Wo[o * 3 + p];
        float s = block_reduce_sum(val, red);
        if (o == 0) out[(size_t)node * 3 + p] = s + bo[p];
    }
}

// ---------------- launcher ----------------
extern "C" void kernel_launch(void* const* d_in, const int* in_sizes, int n_in,
                              void* d_out, int out_size, void* d_ws, size_t ws_size,
                              hipStream_t stream) {
    const float* x   = (const float*)d_in[0];
    const float* ef  = (const float*)d_in[1];
    const int*   fei = (const int*)d_in[2];
    const float* wg0 = (const float*)d_in[3];
    const float* bg0 = (const float*)d_in[4];
    const float* wf0 = (const float*)d_in[5];
    const float* bf0 = (const float*)d_in[6];
    const float* ws0 = (const float*)d_in[7];
    const float* bs0 = (const float*)d_in[8];
    const float* ln0g = (const float*)d_in[9];
    const float* ln0b = (const float*)d_in[10];
    const float* wg1 = (const float*)d_in[11];
    const float* bg1 = (const float*)d_in[12];
    const float* wf1 = (const float*)d_in[13];
    const float* bf1 = (const float*)d_in[14];
    const float* ws1 = (const float*)d_in[15];
    const float* bs1 = (const float*)d_in[16];
    const float* ln1g = (const float*)d_in[17];
    const float* ln1b = (const float*)d_in[18];
    const float* wsk = (const float*)d_in[19];
    const float* bsk = (const float*)d_in[20];
    const float* sWq = (const float*)d_in[21];
    const float* sWk = (const float*)d_in[22];
    const float* sWv = (const float*)d_in[23];
    const float* sWe = (const float*)d_in[24];
    const float* saq = (const float*)d_in[25];
    const float* sak = (const float*)d_in[26];
    const float* sae = (const float*)d_in[27];
    const float* dWq = (const float*)d_in[28];
    const float* dWk = (const float*)d_in[29];
    const float* dWv = (const float*)d_in[30];
    const float* daq = (const float*)d_in[31];
    const float* dak = (const float*)d_in[32];
    const float* E1  = (const float*)d_in[33];
    const float* E2  = (const float*)d_in[34];
    const float* fW1 = (const float*)d_in[35];
    const float* fb1 = (const float*)d_in[36];
    const float* fW2 = (const float*)d_in[37];
    const float* fb2 = (const float*)d_in[38];
    const float* fW3 = (const float*)d_in[39];
    const float* fb3 = (const float*)d_in[40];
    const float* Wo  = (const float*)d_in[41];
    const float* bo  = (const float*)d_in[42];
    float* out = (float*)d_out;

    float* ws = (float*)d_ws;
    // workspace layout (in floats)
    const size_t OFF_X    = 0;          // 6400*768  (X; later reused as Y2 6400*544)
    const size_t OFF_Y1   = 4915200;    // 6400*768  (Y1; later reused as Y3)
    const size_t OFF_HL   = 9830400;    // 6400*256
    const size_t OFF_U    = 11468800;   // 6400*512
    const size_t OFF_W1   = 14745600;   // 768*768
    const size_t OFF_W2   = 15335424;   // 256*544
    const size_t OFF_W3   = 15474688;   // 512*768
    const size_t OFF_AES  = 15867904;   // 16
    const size_t OFF_LOGV = 15867920;   // 400*64
    const size_t OFF_CNT  = 15893520;   // 400 ints
    const size_t OFF_IDX  = 15893920;   // 400*64 ints

    float* X    = ws + OFF_X;
    float* Y1   = ws + OFF_Y1;
    float* HL   = ws + OFF_HL;
    float* U    = ws + OFF_U;
    float* W1   = ws + OFF_W1;
    float* W2   = ws + OFF_W2;
    float* W3   = ws + OFF_W3;
    float* AES  = ws + OFF_AES;
    float* LOGV = ws + OFF_LOGV;
    int*   CNT  = (int*)(ws + OFF_CNT);
    int*   IDX  = (int*)(ws + OFF_IDX);
    float* Y2   = X;   // reuse after G1 consumed X
    float* Y3   = Y1;  // reuse after epi1 consumed Y1

    // weight prep
    build_wcat1<<<(768 * 768 + 255) / 256, 256, 0, stream>>>(wg1, wf1, ws1, W1);
    build_wcat2<<<(256 * 544 + 255) / 256, 256, 0, stream>>>(sWv, dWv, sWq, saq, sWk, sak, dWq, daq, dWk, dak, W2);
    build_wcat3<<<(512 * 768 + 255) / 256, 256, 0, stream>>>(fW1, fW2, fW3, W3);
    build_aes<<<1, 64, 0, stream>>>(sWe, sae, AES);

    // adjacency (batch-independent)
    adj_kernel<<<400, 256, 0, stream>>>(E1, E2, CNT, IDX, LOGV);

    // TCN layer 0 at t in {7,9,11}
    tcn0_kernel<<<NODES, 256, 0, stream>>>(x, wg0, bg0, wf0, bf0, ws0, bs0, ln0g, ln0b, X);

    // G1: Y1 = X (6400x768) @ W1 (768x768)
    gemm_f32<<<dim3(12, 100), 256, 0, stream>>>(NODES, 768, 768, X, 768, W1, 768, Y1, 768);

    // layer-1 epilogue -> hl
    epi1_kernel<<<NODES, 256, 0, stream>>>(Y1, x, bg1, bf1, bs1, ln1g, ln1b, wsk, bsk, HL);

    // G2: Y2 = HL (6400x256) @ W2 (256x544)   [vs | vd | aqs | aks | aqd | akd]
    gemm_f32<<<dim3(9, 100), 256, 0, stream>>>(NODES, 544, 256, HL, 256, W2, 544, Y2, 544);

    // attention stages -> U = [h_fixed | h_adp]
    gat_fixed_kernel<<<NODES, 256, 0, stream>>>(Y2, ef, fei, AES, U);
    gat_adp_kernel<<<NODES, 256, 0, stream>>>(Y2, CNT, IDX, LOGV, U);

    // G3: Y3 = U (6400x512) @ W3 (512x768)
    gemm_f32<<<dim3(12, 100), 256, 0, stream>>>(NODES, 768, 512, U, 512, W3, 768, Y3, 768);

    // fusion + output
    final_kernel<<<NODES, 256, 0, stream>>>(Y3, fb1, fb2, fb3, Wo, bo, out);
}

// Round 2
// 217.740 us; speedup vs baseline: 2.6972x; 2.6972x over previous
//
#include <hip/hip_runtime.h>
#include <math.h>

// Problem constants
#define LL 3600
#define NODES 6400

typedef __attribute__((ext_vector_type(8))) short short8;
typedef __attribute__((ext_vector_type(4))) float f32x4;

// ---------------- bf16 helpers (manual, RN-even) ----------------
__device__ __forceinline__ unsigned short f2bf(float f) {
    unsigned u = __float_as_uint(f);
    unsigned r = (u + 0x7fffu + ((u >> 16) & 1u)) >> 16;
    return (unsigned short)r;
}
__device__ __forceinline__ float bf2f(unsigned short s) {
    return __uint_as_float(((unsigned)s) << 16);
}
__device__ __forceinline__ void split_bf(float v, unsigned short& hi, unsigned short& lo) {
    hi = f2bf(v);
    lo = f2bf(v - bf2f(hi));
}

#define GLOAD16(gp, lp) __builtin_amdgcn_global_load_lds( \
    (const __attribute__((address_space(1))) unsigned int*)(const void*)(gp), \
    (__attribute__((address_space(3))) unsigned int*)(void*)(lp), 16, 0, 0)

// ---------------- block reduce (wave shuffle + 4-way LDS) ----------------
__device__ __forceinline__ void block_reduce_sum2(float a, float b, float* red, float& ra, float& rb) {
    #pragma unroll
    for (int o = 32; o > 0; o >>= 1) { a += __shfl_xor(a, o, 64); b += __shfl_xor(b, o, 64); }
    int w = threadIdx.x >> 6, l = threadIdx.x & 63;
    if (l == 0) { red[w] = a; red[4 + w] = b; }
    __syncthreads();
    ra = red[0] + red[1] + red[2] + red[3];
    rb = red[4] + red[5] + red[6] + red[7];
    __syncthreads();
}
__device__ __forceinline__ float block_reduce_sum(float a, float* red) {
    #pragma unroll
    for (int o = 32; o > 0; o >>= 1) a += __shfl_xor(a, o, 64);
    int w = threadIdx.x >> 6, l = threadIdx.x & 63;
    if (l == 0) red[w] = a;
    __syncthreads();
    float r = red[0] + red[1] + red[2] + red[3];
    __syncthreads();
    return r;
}

// ---------------- weight prep (transposed N x K, hi/lo bf16) ----------------
// W1T[n][k], n = which*256+o (768), k = tt*256+i (768); val = w_which1[o][i][tt]
__global__ __launch_bounds__(256) void build_w1t(
    const float* __restrict__ wg1, const float* __restrict__ wf1,
    const float* __restrict__ ws1,
    unsigned short* __restrict__ Whi, unsigned short* __restrict__ Wlo) {
    int idx = blockIdx.x * 256 + threadIdx.x;
    if (idx >= 768 * 768) return;
    int n = idx / 768, k = idx % 768;
    int which = n >> 8, o = n & 255;
    int tt = k >> 8, i = k & 255;
    const float* w = which == 0 ? wg1 : (which == 1 ? wf1 : ws1);
    float v = w[(o * 256 + i) * 3 + tt];
    split_bf(v, Whi[idx], Wlo[idx]);
}

// W2T[n][k], n in [0,640), k in [0,256)
__global__ __launch_bounds__(256) void build_w2t(
    const float* __restrict__ sWv, const float* __restrict__ dWv,
    const float* __restrict__ sWq, const float* __restrict__ saq,
    const float* __restrict__ sWk, const float* __restrict__ sak,
    const float* __restrict__ dWq, const float* __restrict__ daq,
    const float* __restrict__ dWk, const float* __restrict__ dak,
    unsigned short* __restrict__ Whi, unsigned short* __restrict__ Wlo) {
    int idx = blockIdx.x * 256 + threadIdx.x;
    if (idx >= 640 * 256) return;
    int n = idx / 256, k = idx % 256;
    float v = 0.f;
    if (n < 256) v = sWv[k * 256 + n];
    else if (n < 512) v = dWv[k * 256 + (n - 256)];
    else if (n < 544) {
        int j = n - 512, g = j >> 3, h = j & 7;
        const float* Wm = g == 0 ? sWq : (g == 1 ? sWk : (g == 2 ? dWq : dWk));
        const float* am = g == 0 ? saq : (g == 1 ? sak : (g == 2 ? daq : dak));
        float s = 0.f;
        for (int d = 0; d < 32; d++) s += Wm[k * 256 + h * 32 + d] * am[h * 32 + d];
        v = s;
    }
    split_bf(v, Whi[idx], Wlo[idx]);
}

// W3T[n][k], n in [0,768), k in [0,512)
__global__ __launch_bounds__(256) void build_w3t(
    const float* __restrict__ fW1, const float* __restrict__ fW2,
    const float* __restrict__ fW3,
    unsigned short* __restrict__ Whi, unsigned short* __restrict__ Wlo) {
    int idx = blockIdx.x * 256 + threadIdx.x;
    if (idx >= 768 * 512) return;
    int n = idx / 512, k = idx % 512;
    float v = 0.f;
    if (k < 256) {
        if (n < 256) v = fW1[k * 256 + n];
        else if (n < 512) v = fW2[k * 256 + (n - 256)];
    } else {
        int c = k - 256;
        if (n < 256) v = fW1[c * 256 + n];
        else if (n >= 512) v = fW3[c * 256 + (n - 512)];
    }
    split_bf(v, Whi[idx], Wlo[idx]);
}

// AeS[c*8+h]
__global__ void build_aes(const float* __restrict__ sWe,
                          const float* __restrict__ sae,
                          float* __restrict__ AeS) {
    int tid = threadIdx.x;
    if (tid < 16) {
        int cc = tid / 8, h = tid % 8;
        float s = 0.f;
        for (int d = 0; d < 32; d++) s += sWe[cc * 256 + h * 32 + d] * sae[h * 32 + d];
        AeS[tid] = s;
    }
}

// ---------------- adjacency ----------------
__global__ __launch_bounds__(256) void adj_kernel(
    const float* __restrict__ E1, const float* __restrict__ E2,
    int* __restrict__ cnt, int* __restrict__ idxs, float* __restrict__ logv) {
    int n = blockIdx.x, tid = threadIdx.x;
    __shared__ float a[400];
    __shared__ float m[400];
    __shared__ float e1[10];
    __shared__ float rv[256];
    __shared__ int ri[256];
    if (tid < 10) e1[tid] = E1[n * 10 + tid];
    __syncthreads();
    for (int j = tid; j < 400; j += 256) {
        float sc = 0.f;
        for (int k = 0; k < 10; k++) sc += e1[k] * E2[j * 10 + k];
        a[j] = fmaxf(sc, 0.f);
    }
    __syncthreads();
    float lm = -1e30f;
    for (int j = tid; j < 400; j += 256) lm = fmaxf(lm, a[j]);
    rv[tid] = lm; __syncthreads();
    for (int s = 128; s > 0; s >>= 1) { if (tid < s) rv[tid] = fmaxf(rv[tid], rv[tid + s]); __syncthreads(); }
    float mx = rv[0]; __syncthreads();
    float ls = 0.f;
    for (int j = tid; j < 400; j += 256) { float e = expf(a[j] - mx); a[j] = e; ls += e; }
    rv[tid] = ls; __syncthreads();
    for (int s = 128; s > 0; s >>= 1) { if (tid < s) rv[tid] += rv[tid + s]; __syncthreads(); }
    float den = rv[0]; __syncthreads();
    for (int j = tid; j < 400; j += 256) { a[j] /= den; m[j] = a[j]; }
    __syncthreads();
    for (int p = 0; p < 15; p++) {
        float bv = -1e30f; int bi = 400;
        for (int j = tid; j < 400; j += 256)
            if (m[j] > bv || (m[j] == bv && j < bi)) { bv = m[j]; bi = j; }
        rv[tid] = bv; ri[tid] = bi; __syncthreads();
        for (int s = 128; s > 0; s >>= 1) {
            if (tid < s) {
                if (rv[tid + s] > rv[tid] || (rv[tid + s] == rv[tid] && ri[tid + s] < ri[tid])) {
                    rv[tid] = rv[tid + s]; ri[tid] = ri[tid + s];
                }
            }
            __syncthreads();
        }
        if (tid == 0) m[ri[0]] = -1e30f;
        __syncthreads();
    }
    float bv = -1e30f;
    for (int j = tid; j < 400; j += 256) bv = fmaxf(bv, m[j]);
    rv[tid] = bv; __syncthreads();
    for (int s = 128; s > 0; s >>= 1) { if (tid < s) rv[tid] = fmaxf(rv[tid], rv[tid + s]); __syncthreads(); }
    float kth = rv[0]; __syncthreads();
    if (tid == 0) {
        int c = 0;
        for (int j = 0; j < 400; j++) {
            if (a[j] >= kth && c < 64) {
                idxs[n * 64 + c] = j;
                logv[n * 64 + c] = logf(fmaxf(a[j], 1e-12f));
                c++;
            }
        }
        cnt[n] = c;
    }
}

// ---------------- TCN layer 0 -> Xhi/Xlo (6400 x 768 bf16 pair) ----------------
__global__ __launch_bounds__(256) void tcn0_kernel(
    const float* __restrict__ x,
    const float* __restrict__ wg0, const float* __restrict__ bg0,
    const float* __restrict__ wf0, const float* __restrict__ bf0,
    const float* __restrict__ ws0, const float* __restrict__ bs0,
    const float* __restrict__ lg, const float* __restrict__ lb,
    unsigned short* __restrict__ Xhi, unsigned short* __restrict__ Xlo) {
    int node = blockIdx.x;
    int o = threadIdx.x;
    __shared__ float xs[7][2];
    __shared__ float red[8];
    if (o < 14) { int t = 5 + o / 2, c = o & 1; xs[t - 5][c] = x[(size_t)(node * 12 + t) * 2 + c]; }
    __syncthreads();
    float wg[6], wf[6], ws[6];
    for (int i = 0; i < 6; i++) { wg[i] = wg0[o * 6 + i]; wf[i] = wf0[o * 6 + i]; ws[i] = ws0[o * 6 + i]; }
    float bg = bg0[o], bf = bf0[o], bs = bs0[o];
    float gln = lg[o], bln = lb[o];
    for (int tt = 0; tt < 3; tt++) {
        int t = 7 + 2 * tt;
        float g = bg, f = bf, s = bs;
        for (int k = 0; k < 3; k++) {
            int ti = t - 2 + k - 5;
            for (int c = 0; c < 2; c++) {
                float xv = xs[ti][c];
                g += wg[c * 3 + k] * xv;
                f += wf[c * 3 + k] * xv;
                s += ws[c * 3 + k] * xv;
            }
        }
        float gate = 1.f / (1.f + expf(-g));
        float y = gate * f + (1.f - gate) * s;
        float sum, sq;
        block_reduce_sum2(y, y * y, red, sum, sq);
        float mean = sum * (1.f / 256.f);
        float var = sq * (1.f / 256.f) - mean * mean;
        float v = (y - mean) * rsqrtf(var + 1e-5f) * gln + bln;
        v = fmaxf(v, 0.f);
        size_t p = (size_t)node * 768 + tt * 256 + o;
        split_bf(v, Xhi[p], Xlo[p]);
    }
}

// ---------------- split-bf16 MFMA GEMM: C(MxN) = A(MxK) @ BT(NxK)^T ----------------
// 128x128 tile, 4 waves (2x2 of 64x64), BK=64, mfma_f32_16x16x32_bf16.
// acc += Ahi*Bhi + Ahi*Blo + Alo*Bhi  (split precision ~ fp32)
__global__ __launch_bounds__(256, 2) void gemm_split(
    const unsigned short* __restrict__ Ahi, const unsigned short* __restrict__ Alo,
    const unsigned short* __restrict__ BThi, const unsigned short* __restrict__ BTlo,
    float* __restrict__ C, int K, int ldc) {
    __shared__ __align__(16) unsigned short lAhi[128 * 64];
    __shared__ __align__(16) unsigned short lAlo[128 * 64];
    __shared__ __align__(16) unsigned short lBhi[128 * 64];
    __shared__ __align__(16) unsigned short lBlo[128 * 64];
    int tid = threadIdx.x;
    int lane = tid & 63;
    int w = tid >> 6;
    int wr = w >> 1, wc = w & 1;
    int r = lane & 15, g4 = lane >> 4;
    int row0 = blockIdx.y * 128;
    int col0 = blockIdx.x * 128;
    f32x4 acc[4][4] = {};

    for (int k0 = 0; k0 < K; k0 += 64) {
        __syncthreads();
        #pragma unroll
        for (int it = 0; it < 4; ++it) {
            int c = it * 256 + tid;
            int trow = c >> 3;            // 0..127 (tile row: m for A, n for BT)
            int tk = (c & 7) * 8;         // 0..56 shorts
            size_t ga = (size_t)(row0 + trow) * K + k0 + tk;
            size_t gb = (size_t)(col0 + trow) * K + k0 + tk;
            GLOAD16(Ahi + ga, lAhi + c * 8);
            GLOAD16(Alo + ga, lAlo + c * 8);
            GLOAD16(BThi + gb, lBhi + c * 8);
            GLOAD16(BTlo + gb, lBlo + c * 8);
        }
        asm volatile("s_waitcnt vmcnt(0)" ::: "memory");
        __syncthreads();
        #pragma unroll
        for (int ks = 0; ks < 2; ++ks) {
            int ko = ks * 32 + g4 * 8;
            short8 ah[4], al[4], bh[4], bl[4];
            #pragma unroll
            for (int mi = 0; mi < 4; ++mi) {
                int rr = (wr * 64 + mi * 16 + r) * 64 + ko;
                ah[mi] = *(const short8*)&lAhi[rr];
                al[mi] = *(const short8*)&lAlo[rr];
            }
            #pragma unroll
            for (int ni = 0; ni < 4; ++ni) {
                int rr = (wc * 64 + ni * 16 + r) * 64 + ko;
                bh[ni] = *(const short8*)&lBhi[rr];
                bl[ni] = *(const short8*)&lBlo[rr];
            }
            #pragma unroll
            for (int mi = 0; mi < 4; ++mi)
                #pragma unroll
                for (int ni = 0; ni < 4; ++ni) {
                    acc[mi][ni] = __builtin_amdgcn_mfma_f32_16x16x32_bf16(ah[mi], bh[ni], acc[mi][ni], 0, 0, 0);
                    acc[mi][ni] = __builtin_amdgcn_mfma_f32_16x16x32_bf16(ah[mi], bl[ni], acc[mi][ni], 0, 0, 0);
                    acc[mi][ni] = __builtin_amdgcn_mfma_f32_16x16x32_bf16(al[mi], bh[ni], acc[mi][ni], 0, 0, 0);
                }
        }
    }
    // epilogue: C[row=(lane>>4)*4+reg][col=lane&15] per 16x16 frag
    #pragma unroll
    for (int mi = 0; mi < 4; ++mi) {
        #pragma unroll
        for (int ni = 0; ni < 4; ++ni) {
            int rowb = row0 + wr * 64 + mi * 16 + g4 * 4;
            int colb = col0 + wc * 64 + ni * 16 + r;
            #pragma unroll
            for (int j = 0; j < 4; ++j)
                C[(size_t)(rowb + j) * ldc + colb] = acc[mi][ni][j];
        }
    }
}

// ---------------- layer-1 epilogue -> HLhi/HLlo ----------------
__global__ __launch_bounds__(256) void epi1_kernel(
    const float* __restrict__ Y1, const float* __restrict__ x,
    const float* __restrict__ bg1, const float* __restrict__ bf1, const float* __restrict__ bs1,
    const float* __restrict__ lg, const float* __restrict__ lb,
    const float* __restrict__ wsk, const float* __restrict__ bsk,
    unsigned short* __restrict__ HLhi, unsigned short* __restrict__ HLlo) {
    int node = blockIdx.x, o = threadIdx.x;
    __shared__ float red[8];
    size_t base = (size_t)node * 768;
    float g = Y1[base + o] + bg1[o];
    float f = Y1[base + 256 + o] + bf1[o];
    float s = Y1[base + 512 + o] + bs1[o];
    float gate = 1.f / (1.f + expf(-g));
    float y = gate * f + (1.f - gate) * s;
    float sum, sq;
    block_reduce_sum2(y, y * y, red, sum, sq);
    float mean = sum * (1.f / 256.f);
    float var = sq * (1.f / 256.f) - mean * mean;
    float v = (y - mean) * rsqrtf(var + 1e-5f) * lg[o] + lb[o];
    v = fmaxf(v, 0.f);
    float x0 = x[(size_t)(node * 12 + 11) * 2];
    float x1 = x[(size_t)(node * 12 + 11) * 2 + 1];
    float res = x0 * wsk[o] + x1 * wsk[256 + o] + bsk[o];
    size_t p = (size_t)node * 256 + o;
    split_bf(v + res, HLhi[p], HLlo[p]);
}

// ---------------- fixed-graph GAT -> U cols [0,256) ----------------
__global__ __launch_bounds__(256) void gat_fixed_kernel(
    const float* __restrict__ Y2, const float* __restrict__ ef,
    const int* __restrict__ fei, const float* __restrict__ AeS,
    unsigned short* __restrict__ Uhi, unsigned short* __restrict__ Ulo) {
    int node = blockIdx.x;
    int b = node / 400, n = node % 400;
    int tid = threadIdx.x;
    __shared__ int snd[9];
    __shared__ float sv[9][8];
    __shared__ float al[9][8];
    if (tid < 9) snd[tid] = fei[LL + n * 9 + tid];
    __syncthreads();
    if (tid < 72) {
        int j = tid / 8, h = tid % 8;
        int l = n * 9 + j;
        float e0 = ef[((size_t)b * LL + l) * 2];
        float e1 = ef[((size_t)b * LL + l) * 2 + 1];
        float ae = e0 * AeS[h] + e1 * AeS[8 + h];
        float aq = Y2[(size_t)node * 640 + 512 + h];
        float ak = Y2[((size_t)(b * 400 + snd[j])) * 640 + 520 + h];
        float s = aq + ak + ae;
        s = s > 0.f ? s : 0.2f * s;
        sv[j][h] = s;
    }
    __syncthreads();
    if (tid < 8) {
        int h = tid;
        float mx = -1e30f;
        for (int j = 0; j < 9; j++) mx = fmaxf(mx, sv[j][h]);
        float den = 0.f;
        for (int j = 0; j < 9; j++) { float e = expf(sv[j][h] - mx); al[j][h] = e; den += e; }
        den = fmaxf(den, 1e-12f);
        for (int j = 0; j < 9; j++) al[j][h] /= den;
    }
    __syncthreads();
    int h = tid >> 5, d = tid & 31;
    float acc = 0.f;
    for (int j = 0; j < 9; j++)
        acc += al[j][h] * Y2[((size_t)(b * 400 + snd[j])) * 640 + h * 32 + d];
    float e = acc > 0.f ? acc : (expf(acc) - 1.f);
    size_t p = (size_t)node * 512 + tid;
    split_bf(e, Uhi[p], Ulo[p]);
}

// ---------------- adaptive attention -> U cols [256,512) ----------------
__global__ __launch_bounds__(256) void gat_adp_kernel(
    const float* __restrict__ Y2, const int* __restrict__ cnt,
    const int* __restrict__ idxs, const float* __restrict__ logv,
    unsigned short* __restrict__ Uhi, unsigned short* __restrict__ Ulo) {
    int node = blockIdx.x;
    int b = node / 400, n = node % 400;
    int tid = threadIdx.x;
    __shared__ int jidx[64];
    __shared__ float jlog[64];
    __shared__ float sc[64][8];
    __shared__ float alb[64][8];
    int c = cnt[n];
    if (tid < c) { jidx[tid] = idxs[n * 64 + tid]; jlog[tid] = logv[n * 64 + tid]; }
    __syncthreads();
    for (int e = tid; e < c * 8; e += 256) {
        int j = e / 8, h = e % 8;
        float aq = Y2[(size_t)node * 640 + 528 + h];
        float ak = Y2[((size_t)(b * 400 + jidx[j])) * 640 + 536 + h];
        float s = aq + ak;
        s = s > 0.f ? s : 0.2f * s;
        sc[j][h] = s + jlog[j];
    }
    __syncthreads();
    if (tid < 8) {
        int h = tid; float mx = -1e30f;
        for (int j = 0; j < c; j++) mx = fmaxf(mx, sc[j][h]);
        float den = 0.f;
        for (int j = 0; j < c; j++) { float e = expf(sc[j][h] - mx); alb[j][h] = e; den += e; }
        for (int j = 0; j < c; j++) alb[j][h] /= den;
    }
    __syncthreads();
    int h = tid >> 5, d = tid & 31;
    float acc = 0.f;
    for (int j = 0; j < c; j++)
        acc += alb[j][h] * Y2[((size_t)(b * 400 + jidx[j])) * 640 + 256 + h * 32 + d];
    float e = acc > 0.f ? acc : (expf(acc) - 1.f);
    size_t p = (size_t)node * 512 + 256 + tid;
    split_bf(e, Uhi[p], Ulo[p]);
}

// ---------------- final fuse + output projection ----------------
__global__ __launch_bounds__(256) void final_kernel(
    const float* __restrict__ Y3,
    const float* __restrict__ fb1, const float* __restrict__ fb2, const float* __restrict__ fb3,
    const float* __restrict__ Wo, const float* __restrict__ bo,
    float* __restrict__ out) {
    int node = blockIdx.x, o = threadIdx.x;
    __shared__ float red[8];
    size_t base = (size_t)node * 768;
    float g = 1.f / (1.f + expf(-(Y3[base + o] + fb1[o])));
    float a2 = Y3[base + 256 + o] + fb2[o];
    float a3 = Y3[base + 512 + o] + fb3[o];
    float fused = tanhf(g * a2 + (1.f - g) * a3);
    for (int p = 0; p < 3; p++) {
        float val = fused * Wo[o * 3 + p];
        float s = block_reduce_sum(val, red);
        if (o == 0) out[(size_t)node * 3 + p] = s + bo[p];
    }
}

// ---------------- launcher ----------------
extern "C" void kernel_launch(void* const* d_in, const int* in_sizes, int n_in,
                              void* d_out, int out_size, void* d_ws, size_t ws_size,
                              hipStream_t stream) {
    const float* x   = (const float*)d_in[0];
    const float* ef  = (const float*)d_in[1];
    const int*   fei = (const int*)d_in[2];
    const float* wg0 = (const float*)d_in[3];
    const float* bg0 = (const float*)d_in[4];
    const float* wf0 = (const float*)d_in[5];
    const float* bf0 = (const float*)d_in[6];
    const float* ws0 = (const float*)d_in[7];
    const float* bs0 = (const float*)d_in[8];
    const float* ln0g = (const float*)d_in[9];
    const float* ln0b = (const float*)d_in[10];
    const float* wg1 = (const float*)d_in[11];
    const float* bg1 = (const float*)d_in[12];
    const float* wf1 = (const float*)d_in[13];
    const float* bf1 = (const float*)d_in[14];
    const float* ws1 = (const float*)d_in[15];
    const float* bs1 = (const float*)d_in[16];
    const float* ln1g = (const float*)d_in[17];
    const float* ln1b = (const float*)d_in[18];
    const float* wsk = (const float*)d_in[19];
    const float* bsk = (const float*)d_in[20];
    const float* sWq = (const float*)d_in[21];
    const float* sWk = (const float*)d_in[22];
    const float* sWv = (const float*)d_in[23];
    const float* sWe = (const float*)d_in[24];
    const float* saq = (const float*)d_in[25];
    const float* sak = (const float*)d_in[26];
    const float* sae = (const float*)d_in[27];
    const float* dWq = (const float*)d_in[28];
    const float* dWk = (const float*)d_in[29];
    const float* dWv = (const float*)d_in[30];
    const float* daq = (const float*)d_in[31];
    const float* dak = (const float*)d_in[32];
    const float* E1  = (const float*)d_in[33];
    const float* E2  = (const float*)d_in[34];
    const float* fW1 = (const float*)d_in[35];
    const float* fb1 = (const float*)d_in[36];
    const float* fW2 = (const float*)d_in[37];
    const float* fb2 = (const float*)d_in[38];
    const float* fW3 = (const float*)d_in[39];
    const float* fb3 = (const float*)d_in[40];
    const float* Wo  = (const float*)d_in[41];
    const float* bo  = (const float*)d_in[42];
    float* out = (float*)d_out;

    char* b = (char*)d_ws;
    // byte offsets
    unsigned short* Xhi  = (unsigned short*)(b + 0);          // 9,830,400
    unsigned short* Xlo  = (unsigned short*)(b + 9830400);    // 9,830,400
    float*          Y1   = (float*)(b + 19660800);            // 19,660,800
    unsigned short* HLhi = (unsigned short*)(b + 39321600);   // 3,276,800
    unsigned short* HLlo = (unsigned short*)(b + 42598400);   // 3,276,800
    unsigned short* Uhi  = (unsigned short*)(b + 45875200);   // 6,553,600
    unsigned short* Ulo  = (unsigned short*)(b + 52428800);   // 6,553,600
    unsigned short* W1hi = (unsigned short*)(b + 58982400);   // 1,179,648
    unsigned short* W1lo = (unsigned short*)(b + 60162048);   // 1,179,648
    unsigned short* W2hi = (unsigned short*)(b + 61341696);   // 327,680
    unsigned short* W2lo = (unsigned short*)(b + 61669376);   // 327,680
    unsigned short* W3hi = (unsigned short*)(b + 61997056);   // 786,432
    unsigned short* W3lo = (unsigned short*)(b + 62783488);   // 786,432
    float*          AES  = (float*)(b + 63569920);            // 64 (+pad)
    float*          LOGV = (float*)(b + 63570176);            // 102,400
    int*            CNT  = (int*)(b + 63672576);              // 1,600 (+pad)
    int*            IDX  = (int*)(b + 63674176);              // 102,400
    float*          Y2   = (float*)(b + 0);                   // reuse X region: 16,384,000
    float*          Y3   = Y1;                                // reuse Y1 region

    // weight prep
    build_w1t<<<(768 * 768 + 255) / 256, 256, 0, stream>>>(wg1, wf1, ws1, W1hi, W1lo);
    build_w2t<<<(640 * 256 + 255) / 256, 256, 0, stream>>>(sWv, dWv, sWq, saq, sWk, sak, dWq, daq, dWk, dak, W2hi, W2lo);
    build_w3t<<<(768 * 512 + 255) / 256, 256, 0, stream>>>(fW1, fW2, fW3, W3hi, W3lo);
    build_aes<<<1, 64, 0, stream>>>(sWe, sae, AES);

    // adjacency (batch-independent)
    adj_kernel<<<400, 256, 0, stream>>>(E1, E2, CNT, IDX, LOGV);

    // TCN layer 0
    tcn0_kernel<<<NODES, 256, 0, stream>>>(x, wg0, bg0, wf0, bf0, ws0, bs0, ln0g, ln0b, Xhi, Xlo);

    // G1: Y1 = X @ W1  (M=6400, N=768, K=768)
    gemm_split<<<dim3(6, 50), 256, 0, stream>>>(Xhi, Xlo, W1hi, W1lo, Y1, 768, 768);

    // layer-1 epilogue -> HL
    epi1_kernel<<<NODES, 256, 0, stream>>>(Y1, x, bg1, bf1, bs1, ln1g, ln1b, wsk, bsk, HLhi, HLlo);

    // G2: Y2 = HL @ W2 (M=6400, N=640(pad), K=256)
    gemm_split<<<dim3(5, 50), 256, 0, stream>>>(HLhi, HLlo, W2hi, W2lo, Y2, 256, 640);

    // attention stages -> U
    gat_fixed_kernel<<<NODES, 256, 0, stream>>>(Y2, ef, fei, AES, Uhi, Ulo);
    gat_adp_kernel<<<NODES, 256, 0, stream>>>(Y2, CNT, IDX, LOGV, Uhi, Ulo);

    // G3: Y3 = U @ W3 (M=6400, N=768, K=512)
    gemm_split<<<dim3(6, 50), 256, 0, stream>>>(Uhi, Ulo, W3hi, W3lo, Y3, 512, 768);

    // fusion + output
    final_kernel<<<NODES, 256, 0, stream>>>(Y3, fb1, fb2, fb3, Wo, bo, out);
}

// Round 3
// 179.717 us; speedup vs baseline: 3.2678x; 1.2116x over previous
//
#include <hip/hip_runtime.h>
#include <math.h>

// Problem constants
#define LL 3600
#define NODES 6400

typedef __attribute__((ext_vector_type(8))) short short8;
typedef __attribute__((ext_vector_type(4))) float f32x4;

// ---------------- bf16 helpers (manual, RN-even) ----------------
__device__ __forceinline__ unsigned short f2bf(float f) {
    unsigned u = __float_as_uint(f);
    unsigned r = (u + 0x7fffu + ((u >> 16) & 1u)) >> 16;
    return (unsigned short)r;
}
__device__ __forceinline__ float bf2f(unsigned short s) {
    return __uint_as_float(((unsigned)s) << 16);
}
__device__ __forceinline__ void split_bf(float v, unsigned short& hi, unsigned short& lo) {
    hi = f2bf(v);
    lo = f2bf(v - bf2f(hi));
}

#define GLOAD16(gp, lp) __builtin_amdgcn_global_load_lds( \
    (const __attribute__((address_space(1))) unsigned int*)(const void*)(gp), \
    (__attribute__((address_space(3))) unsigned int*)(void*)(lp), 16, 0, 0)

// ---------------- block reduce (wave shuffle + 4-way LDS) ----------------
__device__ __forceinline__ void block_reduce_sum2(float a, float b, float* red, float& ra, float& rb) {
    #pragma unroll
    for (int o = 32; o > 0; o >>= 1) { a += __shfl_xor(a, o, 64); b += __shfl_xor(b, o, 64); }
    int w = threadIdx.x >> 6, l = threadIdx.x & 63;
    if (l == 0) { red[w] = a; red[4 + w] = b; }
    __syncthreads();
    ra = red[0] + red[1] + red[2] + red[3];
    rb = red[4] + red[5] + red[6] + red[7];
    __syncthreads();
}
__device__ __forceinline__ float block_reduce_sum(float a, float* red) {
    #pragma unroll
    for (int o = 32; o > 0; o >>= 1) a += __shfl_xor(a, o, 64);
    int w = threadIdx.x >> 6, l = threadIdx.x & 63;
    if (l == 0) red[w] = a;
    __syncthreads();
    float r = red[0] + red[1] + red[2] + red[3];
    __syncthreads();
    return r;
}

// ---------------- weight prep (transposed N x K, hi/lo bf16) ----------------
// W1T[n][k], n = which*256+o (768), k = tt*256+i (768); val = w_which1[o][i][tt]
__global__ __launch_bounds__(256) void build_w1t(
    const float* __restrict__ wg1, const float* __restrict__ wf1,
    const float* __restrict__ ws1,
    unsigned short* __restrict__ Whi, unsigned short* __restrict__ Wlo) {
    int idx = blockIdx.x * 256 + threadIdx.x;
    if (idx >= 768 * 768) return;
    int n = idx / 768, k = idx % 768;
    int which = n >> 8, o = n & 255;
    int tt = k >> 8, i = k & 255;
    const float* w = which == 0 ? wg1 : (which == 1 ? wf1 : ws1);
    float v = w[(o * 256 + i) * 3 + tt];
    split_bf(v, Whi[idx], Wlo[idx]);
}

// W2T[n][k], n in [0,640), k in [0,256)
__global__ __launch_bounds__(256) void build_w2t(
    const float* __restrict__ sWv, const float* __restrict__ dWv,
    const float* __restrict__ sWq, const float* __restrict__ saq,
    const float* __restrict__ sWk, const float* __restrict__ sak,
    const float* __restrict__ dWq, const float* __restrict__ daq,
    const float* __restrict__ dWk, const float* __restrict__ dak,
    unsigned short* __restrict__ Whi, unsigned short* __restrict__ Wlo) {
    int idx = blockIdx.x * 256 + threadIdx.x;
    if (idx >= 640 * 256) return;
    int n = idx / 256, k = idx % 256;
    float v = 0.f;
    if (n < 256) v = sWv[k * 256 + n];
    else if (n < 512) v = dWv[k * 256 + (n - 256)];
    else if (n < 544) {
        int j = n - 512, g = j >> 3, h = j & 7;
        const float* Wm = g == 0 ? sWq : (g == 1 ? sWk : (g == 2 ? dWq : dWk));
        const float* am = g == 0 ? saq : (g == 1 ? sak : (g == 2 ? daq : dak));
        float s = 0.f;
        for (int d = 0; d < 32; d++) s += Wm[k * 256 + h * 32 + d] * am[h * 32 + d];
        v = s;
    }
    split_bf(v, Whi[idx], Wlo[idx]);
}

// W3T[n][k], n in [0,768), k in [0,512)
__global__ __launch_bounds__(256) void build_w3t(
    const float* __restrict__ fW1, const float* __restrict__ fW2,
    const float* __restrict__ fW3,
    unsigned short* __restrict__ Whi, unsigned short* __restrict__ Wlo) {
    int idx = blockIdx.x * 256 + threadIdx.x;
    if (idx >= 768 * 512) return;
    int n = idx / 512, k = idx % 512;
    float v = 0.f;
    if (k < 256) {
        if (n < 256) v = fW1[k * 256 + n];
        else if (n < 512) v = fW2[k * 256 + (n - 256)];
    } else {
        int c = k - 256;
        if (n < 256) v = fW1[c * 256 + n];
        else if (n >= 512) v = fW3[c * 256 + (n - 512)];
    }
    split_bf(v, Whi[idx], Wlo[idx]);
}

// AeS[c*8+h]
__global__ void build_aes(const float* __restrict__ sWe,
                          const float* __restrict__ sae,
                          float* __restrict__ AeS) {
    int tid = threadIdx.x;
    if (tid < 16) {
        int cc = tid / 8, h = tid % 8;
        float s = 0.f;
        for (int d = 0; d < 32; d++) s += sWe[cc * 256 + h * 32 + d] * sae[h * 32 + d];
        AeS[tid] = s;
    }
}

// ---------------- adjacency: one WAVE per row, all-register top-16 ----------------
__global__ __launch_bounds__(256) void adj_kernel(
    const float* __restrict__ E1, const float* __restrict__ E2,
    int* __restrict__ cnt, int* __restrict__ idxs, float* __restrict__ logv) {
    int n = (blockIdx.x * 256 + threadIdx.x) >> 6;
    int lane = threadIdx.x & 63;
    if (n >= 400) return;
    float e1[10];
    #pragma unroll
    for (int k = 0; k < 10; k++) e1[k] = E1[n * 10 + k];
    // scores (relu), 7 columns per lane: j = i*64 + lane
    float p[7];
    #pragma unroll
    for (int i = 0; i < 7; i++) {
        int j = i * 64 + lane;
        if (j < 400) {
            float s = 0.f;
            #pragma unroll
            for (int k = 0; k < 10; k++) s += e1[k] * E2[j * 10 + k];
            p[i] = fmaxf(s, 0.f);
        } else p[i] = -1e30f;
    }
    // row max
    float mx = -1e30f;
    #pragma unroll
    for (int i = 0; i < 7; i++) mx = fmaxf(mx, p[i]);
    #pragma unroll
    for (int o = 32; o > 0; o >>= 1) mx = fmaxf(mx, __shfl_xor(mx, o, 64));
    // softmax
    float sum = 0.f;
    #pragma unroll
    for (int i = 0; i < 7; i++) {
        int j = i * 64 + lane;
        if (j < 400) { p[i] = expf(p[i] - mx); sum += p[i]; }
    }
    #pragma unroll
    for (int o = 32; o > 0; o >>= 1) sum += __shfl_xor(sum, o, 64);
    float inv = 1.f / sum;
    float m[7];
    #pragma unroll
    for (int i = 0; i < 7; i++) {
        int j = i * 64 + lane;
        if (j < 400) { p[i] *= inv; m[i] = p[i]; }
        else m[i] = -1e30f;
    }
    // remove 15 successive maxima (one instance each)
    for (int it = 0; it < 15; ++it) {
        float lm = m[0];
        #pragma unroll
        for (int i = 1; i < 7; i++) lm = fmaxf(lm, m[i]);
        float gm = lm;
        #pragma unroll
        for (int o = 32; o > 0; o >>= 1) gm = fmaxf(gm, __shfl_xor(gm, o, 64));
        unsigned long long msk = __ballot(lm == gm);
        int first = (int)(__ffsll((long long)msk)) - 1;
        if (lane == first) {
            #pragma unroll
            for (int i = 0; i < 7; i++) {
                if (m[i] == gm) { m[i] = -1e30f; break; }
            }
        }
    }
    // kth = max of remainder (16th largest)
    float kth = m[0];
    #pragma unroll
    for (int i = 1; i < 7; i++) kth = fmaxf(kth, m[i]);
    #pragma unroll
    for (int o = 32; o > 0; o >>= 1) kth = fmaxf(kth, __shfl_xor(kth, o, 64));
    // ordered compaction of entries >= kth
    int base = 0;
    #pragma unroll
    for (int i = 0; i < 7; i++) {
        int j = i * 64 + lane;
        bool pred = (j < 400) && (p[i] >= kth);
        unsigned long long msk = __ballot(pred);
        int pre = __popcll(msk & ((lane == 63) ? 0x7fffffffffffffffull : ((1ull << lane) - 1)));
        if (pred) {
            int pos = base + pre;
            if (pos < 64) {
                idxs[n * 64 + pos] = j;
                logv[n * 64 + pos] = logf(fmaxf(p[i], 1e-12f));
            }
        }
        base += __popcll(msk);
    }
    if (lane == 0) cnt[n] = base < 64 ? base : 64;
}

// ---------------- TCN layer 0 -> Xhi/Xlo (6400 x 768 bf16 pair) ----------------
__global__ __launch_bounds__(256) void tcn0_kernel(
    const float* __restrict__ x,
    const float* __restrict__ wg0, const float* __restrict__ bg0,
    const float* __restrict__ wf0, const float* __restrict__ bf0,
    const float* __restrict__ ws0, const float* __restrict__ bs0,
    const float* __restrict__ lg, const float* __restrict__ lb,
    unsigned short* __restrict__ Xhi, unsigned short* __restrict__ Xlo) {
    int node = blockIdx.x;
    int o = threadIdx.x;
    __shared__ float xs[7][2];
    __shared__ float red[8];
    if (o < 14) { int t = 5 + o / 2, c = o & 1; xs[t - 5][c] = x[(size_t)(node * 12 + t) * 2 + c]; }
    __syncthreads();
    float wg[6], wf[6], ws[6];
    for (int i = 0; i < 6; i++) { wg[i] = wg0[o * 6 + i]; wf[i] = wf0[o * 6 + i]; ws[i] = ws0[o * 6 + i]; }
    float bg = bg0[o], bf = bf0[o], bs = bs0[o];
    float gln = lg[o], bln = lb[o];
    for (int tt = 0; tt < 3; tt++) {
        int t = 7 + 2 * tt;
        float g = bg, f = bf, s = bs;
        for (int k = 0; k < 3; k++) {
            int ti = t - 2 + k - 5;
            for (int c = 0; c < 2; c++) {
                float xv = xs[ti][c];
                g += wg[c * 3 + k] * xv;
                f += wf[c * 3 + k] * xv;
                s += ws[c * 3 + k] * xv;
            }
        }
        float gate = 1.f / (1.f + expf(-g));
        float y = gate * f + (1.f - gate) * s;
        float sum, sq;
        block_reduce_sum2(y, y * y, red, sum, sq);
        float mean = sum * (1.f / 256.f);
        float var = sq * (1.f / 256.f) - mean * mean;
        float v = (y - mean) * rsqrtf(var + 1e-5f) * gln + bln;
        v = fmaxf(v, 0.f);
        size_t p = (size_t)node * 768 + tt * 256 + o;
        split_bf(v, Xhi[p], Xlo[p]);
    }
}

// ---------------- split-bf16 MFMA GEMM: C(MxN) = A(MxK) @ BT(NxK)^T ----------------
__global__ __launch_bounds__(256, 2) void gemm_split(
    const unsigned short* __restrict__ Ahi, const unsigned short* __restrict__ Alo,
    const unsigned short* __restrict__ BThi, const unsigned short* __restrict__ BTlo,
    float* __restrict__ C, int K, int ldc) {
    __shared__ __align__(16) unsigned short lAhi[128 * 64];
    __shared__ __align__(16) unsigned short lAlo[128 * 64];
    __shared__ __align__(16) unsigned short lBhi[128 * 64];
    __shared__ __align__(16) unsigned short lBlo[128 * 64];
    int tid = threadIdx.x;
    int lane = tid & 63;
    int w = tid >> 6;
    int wr = w >> 1, wc = w & 1;
    int r = lane & 15, g4 = lane >> 4;
    int row0 = blockIdx.y * 128;
    int col0 = blockIdx.x * 128;
    f32x4 acc[4][4] = {};

    for (int k0 = 0; k0 < K; k0 += 64) {
        __syncthreads();
        #pragma unroll
        for (int it = 0; it < 4; ++it) {
            int c = it * 256 + tid;
            int trow = c >> 3;
            int tk = (c & 7) * 8;
            size_t ga = (size_t)(row0 + trow) * K + k0 + tk;
            size_t gb = (size_t)(col0 + trow) * K + k0 + tk;
            GLOAD16(Ahi + ga, lAhi + c * 8);
            GLOAD16(Alo + ga, lAlo + c * 8);
            GLOAD16(BThi + gb, lBhi + c * 8);
            GLOAD16(BTlo + gb, lBlo + c * 8);
        }
        asm volatile("s_waitcnt vmcnt(0)" ::: "memory");
        __syncthreads();
        #pragma unroll
        for (int ks = 0; ks < 2; ++ks) {
            int ko = ks * 32 + g4 * 8;
            short8 ah[4], al[4], bh[4], bl[4];
            #pragma unroll
            for (int mi = 0; mi < 4; ++mi) {
                int rr = (wr * 64 + mi * 16 + r) * 64 + ko;
                ah[mi] = *(const short8*)&lAhi[rr];
                al[mi] = *(const short8*)&lAlo[rr];
            }
            #pragma unroll
            for (int ni = 0; ni < 4; ++ni) {
                int rr = (wc * 64 + ni * 16 + r) * 64 + ko;
                bh[ni] = *(const short8*)&lBhi[rr];
                bl[ni] = *(const short8*)&lBlo[rr];
            }
            #pragma unroll
            for (int mi = 0; mi < 4; ++mi)
                #pragma unroll
                for (int ni = 0; ni < 4; ++ni) {
                    acc[mi][ni] = __builtin_amdgcn_mfma_f32_16x16x32_bf16(ah[mi], bh[ni], acc[mi][ni], 0, 0, 0);
                    acc[mi][ni] = __builtin_amdgcn_mfma_f32_16x16x32_bf16(ah[mi], bl[ni], acc[mi][ni], 0, 0, 0);
                    acc[mi][ni] = __builtin_amdgcn_mfma_f32_16x16x32_bf16(al[mi], bh[ni], acc[mi][ni], 0, 0, 0);
                }
        }
    }
    #pragma unroll
    for (int mi = 0; mi < 4; ++mi) {
        #pragma unroll
        for (int ni = 0; ni < 4; ++ni) {
            int rowb = row0 + wr * 64 + mi * 16 + g4 * 4;
            int colb = col0 + wc * 64 + ni * 16 + r;
            #pragma unroll
            for (int j = 0; j < 4; ++j)
                C[(size_t)(rowb + j) * ldc + colb] = acc[mi][ni][j];
        }
    }
}

// ---------------- layer-1 epilogue -> HLhi/HLlo ----------------
__global__ __launch_bounds__(256) void epi1_kernel(
    const float* __restrict__ Y1, const float* __restrict__ x,
    const float* __restrict__ bg1, const float* __restrict__ bf1, const float* __restrict__ bs1,
    const float* __restrict__ lg, const float* __restrict__ lb,
    const float* __restrict__ wsk, const float* __restrict__ bsk,
    unsigned short* __restrict__ HLhi, unsigned short* __restrict__ HLlo) {
    int node = blockIdx.x, o = threadIdx.x;
    __shared__ float red[8];
    size_t base = (size_t)node * 768;
    float g = Y1[base + o] + bg1[o];
    float f = Y1[base + 256 + o] + bf1[o];
    float s = Y1[base + 512 + o] + bs1[o];
    float gate = 1.f / (1.f + expf(-g));
    float y = gate * f + (1.f - gate) * s;
    float sum, sq;
    block_reduce_sum2(y, y * y, red, sum, sq);
    float mean = sum * (1.f / 256.f);
    float var = sq * (1.f / 256.f) - mean * mean;
    float v = (y - mean) * rsqrtf(var + 1e-5f) * lg[o] + lb[o];
    v = fmaxf(v, 0.f);
    float x0 = x[(size_t)(node * 12 + 11) * 2];
    float x1 = x[(size_t)(node * 12 + 11) * 2 + 1];
    float res = x0 * wsk[o] + x1 * wsk[256 + o] + bsk[o];
    size_t p = (size_t)node * 256 + o;
    split_bf(v + res, HLhi[p], HLlo[p]);
}

// ---------------- fixed-graph GAT -> U cols [0,256) ----------------
__global__ __launch_bounds__(256) void gat_fixed_kernel(
    const float* __restrict__ Y2, const float* __restrict__ ef,
    const int* __restrict__ fei, const float* __restrict__ AeS,
    unsigned short* __restrict__ Uhi, unsigned short* __restrict__ Ulo) {
    int node = blockIdx.x;
    int b = node / 400, n = node % 400;
    int tid = threadIdx.x;
    __shared__ int snd[9];
    __shared__ float sv[9][8];
    __shared__ float al[9][8];
    if (tid < 9) snd[tid] = fei[LL + n * 9 + tid];
    __syncthreads();
    if (tid < 72) {
        int j = tid / 8, h = tid % 8;
        int l = n * 9 + j;
        float e0 = ef[((size_t)b * LL + l) * 2];
        float e1 = ef[((size_t)b * LL + l) * 2 + 1];
        float ae = e0 * AeS[h] + e1 * AeS[8 + h];
        float aq = Y2[(size_t)node * 640 + 512 + h];
        float ak = Y2[((size_t)(b * 400 + snd[j])) * 640 + 520 + h];
        float s = aq + ak + ae;
        s = s > 0.f ? s : 0.2f * s;
        sv[j][h] = s;
    }
    __syncthreads();
    if (tid < 8) {
        int h = tid;
        float mx = -1e30f;
        for (int j = 0; j < 9; j++) mx = fmaxf(mx, sv[j][h]);
        float den = 0.f;
        for (int j = 0; j < 9; j++) { float e = expf(sv[j][h] - mx); al[j][h] = e; den += e; }
        den = fmaxf(den, 1e-12f);
        for (int j = 0; j < 9; j++) al[j][h] /= den;
    }
    __syncthreads();
    int h = tid >> 5, d = tid & 31;
    float acc = 0.f;
    for (int j = 0; j < 9; j++)
        acc += al[j][h] * Y2[((size_t)(b * 400 + snd[j])) * 640 + h * 32 + d];
    float e = acc > 0.f ? acc : (expf(acc) - 1.f);
    size_t p = (size_t)node * 512 + tid;
    split_bf(e, Uhi[p], Ulo[p]);
}

// ---------------- adaptive attention -> U cols [256,512) ----------------
__global__ __launch_bounds__(256) void gat_adp_kernel(
    const float* __restrict__ Y2, const int* __restrict__ cnt,
    const int* __restrict__ idxs, const float* __restrict__ logv,
    unsigned short* __restrict__ Uhi, unsigned short* __restrict__ Ulo) {
    int node = blockIdx.x;
    int b = node / 400, n = node % 400;
    int tid = threadIdx.x;
    __shared__ int jidx[64];
    __shared__ float jlog[64];
    __shared__ float sc[64][8];
    __shared__ float alb[64][8];
    int c = cnt[n];
    if (tid < c) { jidx[tid] = idxs[n * 64 + tid]; jlog[tid] = logv[n * 64 + tid]; }
    __syncthreads();
    for (int e = tid; e < c * 8; e += 256) {
        int j = e / 8, h = e % 8;
        float aq = Y2[(size_t)node * 640 + 528 + h];
        float ak = Y2[((size_t)(b * 400 + jidx[j])) * 640 + 536 + h];
        float s = aq + ak;
        s = s > 0.f ? s : 0.2f * s;
        sc[j][h] = s + jlog[j];
    }
    __syncthreads();
    if (tid < 8) {
        int h = tid; float mx = -1e30f;
        for (int j = 0; j < c; j++) mx = fmaxf(mx, sc[j][h]);
        float den = 0.f;
        for (int j = 0; j < c; j++) { float e = expf(sc[j][h] - mx); alb[j][h] = e; den += e; }
        for (int j = 0; j < c; j++) alb[j][h] /= den;
    }
    __syncthreads();
    int h = tid >> 5, d = tid & 31;
    float acc = 0.f;
    for (int j = 0; j < c; j++)
        acc += alb[j][h] * Y2[((size_t)(b * 400 + jidx[j])) * 640 + 256 + h * 32 + d];
    float e = acc > 0.f ? acc : (expf(acc) - 1.f);
    size_t p = (size_t)node * 512 + 256 + tid;
    split_bf(e, Uhi[p], Ulo[p]);
}

// ---------------- final fuse + output projection ----------------
__global__ __launch_bounds__(256) void final_kernel(
    const float* __restrict__ Y3,
    const float* __restrict__ fb1, const float* __restrict__ fb2, const float* __restrict__ fb3,
    const float* __restrict__ Wo, const float* __restrict__ bo,
    float* __restrict__ out) {
    int node = blockIdx.x, o = threadIdx.x;
    __shared__ float red[8];
    size_t base = (size_t)node * 768;
    float g = 1.f / (1.f + expf(-(Y3[base + o] + fb1[o])));
    float a2 = Y3[base + 256 + o] + fb2[o];
    float a3 = Y3[base + 512 + o] + fb3[o];
    float fused = tanhf(g * a2 + (1.f - g) * a3);
    for (int p = 0; p < 3; p++) {
        float val = fused * Wo[o * 3 + p];
        float s = block_reduce_sum(val, red);
        if (o == 0) out[(size_t)node * 3 + p] = s + bo[p];
    }
}

// ---------------- launcher ----------------
extern "C" void kernel_launch(void* const* d_in, const int* in_sizes, int n_in,
                              void* d_out, int out_size, void* d_ws, size_t ws_size,
                              hipStream_t stream) {
    const float* x   = (const float*)d_in[0];
    const float* ef  = (const float*)d_in[1];
    const int*   fei = (const int*)d_in[2];
    const float* wg0 = (const float*)d_in[3];
    const float* bg0 = (const float*)d_in[4];
    const float* wf0 = (const float*)d_in[5];
    const float* bf0 = (const float*)d_in[6];
    const float* ws0 = (const float*)d_in[7];
    const float* bs0 = (const float*)d_in[8];
    const float* ln0g = (const float*)d_in[9];
    const float* ln0b = (const float*)d_in[10];
    const float* wg1 = (const float*)d_in[11];
    const float* bg1 = (const float*)d_in[12];
    const float* wf1 = (const float*)d_in[13];
    const float* bf1 = (const float*)d_in[14];
    const float* ws1 = (const float*)d_in[15];
    const float* bs1 = (const float*)d_in[16];
    const float* ln1g = (const float*)d_in[17];
    const float* ln1b = (const float*)d_in[18];
    const float* wsk = (const float*)d_in[19];
    const float* bsk = (const float*)d_in[20];
    const float* sWq = (const float*)d_in[21];
    const float* sWk = (const float*)d_in[22];
    const float* sWv = (const float*)d_in[23];
    const float* sWe = (const float*)d_in[24];
    const float* saq = (const float*)d_in[25];
    const float* sak = (const float*)d_in[26];
    const float* sae = (const float*)d_in[27];
    const float* dWq = (const float*)d_in[28];
    const float* dWk = (const float*)d_in[29];
    const float* dWv = (const float*)d_in[30];
    const float* daq = (const float*)d_in[31];
    const float* dak = (const float*)d_in[32];
    const float* E1  = (const float*)d_in[33];
    const float* E2  = (const float*)d_in[34];
    const float* fW1 = (const float*)d_in[35];
    const float* fb1 = (const float*)d_in[36];
    const float* fW2 = (const float*)d_in[37];
    const float* fb2 = (const float*)d_in[38];
    const float* fW3 = (const float*)d_in[39];
    const float* fb3 = (const float*)d_in[40];
    const float* Wo  = (const float*)d_in[41];
    const float* bo  = (const float*)d_in[42];
    float* out = (float*)d_out;

    char* b = (char*)d_ws;
    unsigned short* Xhi  = (unsigned short*)(b + 0);
    unsigned short* Xlo  = (unsigned short*)(b + 9830400);
    float*          Y1   = (float*)(b + 19660800);
    unsigned short* HLhi = (unsigned short*)(b + 39321600);
    unsigned short* HLlo = (unsigned short*)(b + 42598400);
    unsigned short* Uhi  = (unsigned short*)(b + 45875200);
    unsigned short* Ulo  = (unsigned short*)(b + 52428800);
    unsigned short* W1hi = (unsigned short*)(b + 58982400);
    unsigned short* W1lo = (unsigned short*)(b + 60162048);
    unsigned short* W2hi = (unsigned short*)(b + 61341696);
    unsigned short* W2lo = (unsigned short*)(b + 61669376);
    unsigned short* W3hi = (unsigned short*)(b + 61997056);
    unsigned short* W3lo = (unsigned short*)(b + 62783488);
    float*          AES  = (float*)(b + 63569920);
    float*          LOGV = (float*)(b + 63570176);
    int*            CNT  = (int*)(b + 63672576);
    int*            IDX  = (int*)(b + 63674176);
    float*          Y2   = (float*)(b + 0);
    float*          Y3   = Y1;

    build_w1t<<<(768 * 768 + 255) / 256, 256, 0, stream>>>(wg1, wf1, ws1, W1hi, W1lo);
    build_w2t<<<(640 * 256 + 255) / 256, 256, 0, stream>>>(sWv, dWv, sWq, saq, sWk, sak, dWq, daq, dWk, dak, W2hi, W2lo);
    build_w3t<<<(768 * 512 + 255) / 256, 256, 0, stream>>>(fW1, fW2, fW3, W3hi, W3lo);
    build_aes<<<1, 64, 0, stream>>>(sWe, sae, AES);

    // adjacency: 400 waves, 100 blocks
    adj_kernel<<<100, 256, 0, stream>>>(E1, E2, CNT, IDX, LOGV);

    tcn0_kernel<<<NODES, 256, 0, stream>>>(x, wg0, bg0, wf0, bf0, ws0, bs0, ln0g, ln0b, Xhi, Xlo);

    gemm_split<<<dim3(6, 50), 256, 0, stream>>>(Xhi, Xlo, W1hi, W1lo, Y1, 768, 768);

    epi1_kernel<<<NODES, 256, 0, stream>>>(Y1, x, bg1, bf1, bs1, ln1g, ln1b, wsk, bsk, HLhi, HLlo);

    gemm_split<<<dim3(5, 50), 256, 0, stream>>>(HLhi, HLlo, W2hi, W2lo, Y2, 256, 640);

    gat_fixed_kernel<<<NODES, 256, 0, stream>>>(Y2, ef, fei, AES, Uhi, Ulo);
    gat_adp_kernel<<<NODES, 256, 0, stream>>>(Y2, CNT, IDX, LOGV, Uhi, Ulo);

    gemm_split<<<dim3(6, 50), 256, 0, stream>>>(Uhi, Ulo, W3hi, W3lo, Y3, 512, 768);

    final_kernel<<<NODES, 256, 0, stream>>>(Y3, fb1, fb2, fb3, Wo, bo, out);
}

// Round 4
// 166.177 us; speedup vs baseline: 3.5340x; 1.0815x over previous
//
#include <hip/hip_runtime.h>
#include <math.h>

// Problem constants
#define LL 3600
#define NODES 6400

typedef __attribute__((ext_vector_type(8))) short short8;
typedef __attribute__((ext_vector_type(4))) float f32x4;

// ---------------- bf16 helpers (manual, RN-even) ----------------
__device__ __forceinline__ unsigned short f2bf(float f) {
    unsigned u = __float_as_uint(f);
    unsigned r = (u + 0x7fffu + ((u >> 16) & 1u)) >> 16;
    return (unsigned short)r;
}
__device__ __forceinline__ float bf2f(unsigned short s) {
    return __uint_as_float(((unsigned)s) << 16);
}
__device__ __forceinline__ void split_bf(float v, unsigned short& hi, unsigned short& lo) {
    hi = f2bf(v);
    lo = f2bf(v - bf2f(hi));
}

#define GLOAD16(gp, lp) __builtin_amdgcn_global_load_lds( \
    (const __attribute__((address_space(1))) unsigned int*)(const void*)(gp), \
    (__attribute__((address_space(3))) unsigned int*)(void*)(lp), 16, 0, 0)

// ---------------- block reduce (wave shuffle + 4-way LDS) ----------------
__device__ __forceinline__ void block_reduce_sum2(float a, float b, float* red, float& ra, float& rb) {
    #pragma unroll
    for (int o = 32; o > 0; o >>= 1) { a += __shfl_xor(a, o, 64); b += __shfl_xor(b, o, 64); }
    int w = threadIdx.x >> 6, l = threadIdx.x & 63;
    if (l == 0) { red[w] = a; red[4 + w] = b; }
    __syncthreads();
    ra = red[0] + red[1] + red[2] + red[3];
    rb = red[4] + red[5] + red[6] + red[7];
    __syncthreads();
}

// ================= MEGA PREP KERNEL =================
// blocks [0,2304): W1T  | [2304,2944): W2T | [2944,4480): W3T
// [4480]: AeS | [4481,4581): adj | [4581,10981): tcn0
__global__ __launch_bounds__(256) void prep_kernel(
    const float* __restrict__ wg1, const float* __restrict__ wf1, const float* __restrict__ ws1,
    const float* __restrict__ sWv, const float* __restrict__ dWv,
    const float* __restrict__ sWq, const float* __restrict__ saq,
    const float* __restrict__ sWk, const float* __restrict__ sak,
    const float* __restrict__ dWq, const float* __restrict__ daq,
    const float* __restrict__ dWk, const float* __restrict__ dak,
    const float* __restrict__ fW1, const float* __restrict__ fW2, const float* __restrict__ fW3,
    const float* __restrict__ sWe, const float* __restrict__ sae,
    const float* __restrict__ E1, const float* __restrict__ E2,
    const float* __restrict__ x,
    const float* __restrict__ wg0, const float* __restrict__ bg0,
    const float* __restrict__ wf0, const float* __restrict__ bf0,
    const float* __restrict__ ws0, const float* __restrict__ bs0,
    const float* __restrict__ lg0, const float* __restrict__ lb0,
    unsigned short* __restrict__ W1hi, unsigned short* __restrict__ W1lo,
    unsigned short* __restrict__ W2hi, unsigned short* __restrict__ W2lo,
    unsigned short* __restrict__ W3hi, unsigned short* __restrict__ W3lo,
    float* __restrict__ AeS,
    int* __restrict__ cnt, int* __restrict__ idxs, float* __restrict__ logv,
    unsigned short* __restrict__ Xhi, unsigned short* __restrict__ Xlo) {
    __shared__ float smem[22];   // tcn0: xs[14] + red[8]
    int bid = blockIdx.x;
    int tid = threadIdx.x;

    if (bid < 2304) {
        // ---- W1T[n][k]: n = which*256+o, k = tt*256+i; val = w1[o][i][tt]
        int idx = bid * 256 + tid;
        int n = idx / 768, k = idx % 768;
        int which = n >> 8, o = n & 255;
        int tt = k >> 8, i = k & 255;
        const float* w = which == 0 ? wg1 : (which == 1 ? wf1 : ws1);
        float v = w[(o * 256 + i) * 3 + tt];
        split_bf(v, W1hi[idx], W1lo[idx]);
    } else if (bid < 2944) {
        // ---- W2T[n][k], n in [0,640), k in [0,256)
        int idx = (bid - 2304) * 256 + tid;
        int n = idx / 256, k = idx % 256;
        float v = 0.f;
        if (n < 256) v = sWv[k * 256 + n];
        else if (n < 512) v = dWv[k * 256 + (n - 256)];
        else if (n < 544) {
            int j = n - 512, g = j >> 3, h = j & 7;
            const float* Wm = g == 0 ? sWq : (g == 1 ? sWk : (g == 2 ? dWq : dWk));
            const float* am = g == 0 ? saq : (g == 1 ? sak : (g == 2 ? daq : dak));
            float s = 0.f;
            for (int d = 0; d < 32; d++) s += Wm[k * 256 + h * 32 + d] * am[h * 32 + d];
            v = s;
        }
        split_bf(v, W2hi[idx], W2lo[idx]);
    } else if (bid < 4480) {
        // ---- W3T[n][k], n in [0,768), k in [0,512)
        int idx = (bid - 2944) * 256 + tid;
        int n = idx / 512, k = idx % 512;
        float v = 0.f;
        if (k < 256) {
            if (n < 256) v = fW1[k * 256 + n];
            else if (n < 512) v = fW2[k * 256 + (n - 256)];
        } else {
            int c = k - 256;
            if (n < 256) v = fW1[c * 256 + n];
            else if (n >= 512) v = fW3[c * 256 + (n - 512)];
        }
        split_bf(v, W3hi[idx], W3lo[idx]);
    } else if (bid == 4480) {
        if (tid < 16) {
            int cc = tid / 8, h = tid % 8;
            float s = 0.f;
            for (int d = 0; d < 32; d++) s += sWe[cc * 256 + h * 32 + d] * sae[h * 32 + d];
            AeS[tid] = s;
        }
    } else if (bid < 4581) {
        // ---- adjacency: one wave per row
        int n = ((bid - 4481) * 256 + tid) >> 6;
        int lane = tid & 63;
        if (n >= 400) return;
        float e1[10];
        #pragma unroll
        for (int k = 0; k < 10; k++) e1[k] = E1[n * 10 + k];
        float p[7];
        #pragma unroll
        for (int i = 0; i < 7; i++) {
            int j = i * 64 + lane;
            if (j < 400) {
                float s = 0.f;
                #pragma unroll
                for (int k = 0; k < 10; k++) s += e1[k] * E2[j * 10 + k];
                p[i] = fmaxf(s, 0.f);
            } else p[i] = -1e30f;
        }
        float mx = -1e30f;
        #pragma unroll
        for (int i = 0; i < 7; i++) mx = fmaxf(mx, p[i]);
        #pragma unroll
        for (int o = 32; o > 0; o >>= 1) mx = fmaxf(mx, __shfl_xor(mx, o, 64));
        float sum = 0.f;
        #pragma unroll
        for (int i = 0; i < 7; i++) {
            int j = i * 64 + lane;
            if (j < 400) { p[i] = expf(p[i] - mx); sum += p[i]; }
        }
        #pragma unroll
        for (int o = 32; o > 0; o >>= 1) sum += __shfl_xor(sum, o, 64);
        float inv = 1.f / sum;
        float m[7];
        #pragma unroll
        for (int i = 0; i < 7; i++) {
            int j = i * 64 + lane;
            if (j < 400) { p[i] *= inv; m[i] = p[i]; }
            else m[i] = -1e30f;
        }
        for (int it = 0; it < 15; ++it) {
            float lm = m[0];
            #pragma unroll
            for (int i = 1; i < 7; i++) lm = fmaxf(lm, m[i]);
            float gm = lm;
            #pragma unroll
            for (int o = 32; o > 0; o >>= 1) gm = fmaxf(gm, __shfl_xor(gm, o, 64));
            unsigned long long msk = __ballot(lm == gm);
            int first = (int)(__ffsll((long long)msk)) - 1;
            if (lane == first) {
                #pragma unroll
                for (int i = 0; i < 7; i++) {
                    if (m[i] == gm) { m[i] = -1e30f; break; }
                }
            }
        }
        float kth = m[0];
        #pragma unroll
        for (int i = 1; i < 7; i++) kth = fmaxf(kth, m[i]);
        #pragma unroll
        for (int o = 32; o > 0; o >>= 1) kth = fmaxf(kth, __shfl_xor(kth, o, 64));
        int base = 0;
        #pragma unroll
        for (int i = 0; i < 7; i++) {
            int j = i * 64 + lane;
            bool pred = (j < 400) && (p[i] >= kth);
            unsigned long long msk = __ballot(pred);
            int pre = __popcll(msk & ((lane == 63) ? 0x7fffffffffffffffull : ((1ull << lane) - 1)));
            if (pred) {
                int pos = base + pre;
                if (pos < 64) {
                    idxs[n * 64 + pos] = j;
                    logv[n * 64 + pos] = logf(fmaxf(p[i], 1e-12f));
                }
            }
            base += __popcll(msk);
        }
        if (lane == 0) cnt[n] = base < 64 ? base : 64;
    } else {
        // ---- TCN layer 0
        int node = bid - 4581;
        int o = tid;
        float* xs = smem;        // [7][2]
        float* red = smem + 14;  // [8]
        if (o < 14) { int t = 5 + o / 2, c = o & 1; xs[(t - 5) * 2 + c] = x[(size_t)(node * 12 + t) * 2 + c]; }
        __syncthreads();
        float wg[6], wf[6], wsv[6];
        for (int i = 0; i < 6; i++) { wg[i] = wg0[o * 6 + i]; wf[i] = wf0[o * 6 + i]; wsv[i] = ws0[o * 6 + i]; }
        float bg = bg0[o], bf = bf0[o], bs = bs0[o];
        float gln = lg0[o], bln = lb0[o];
        for (int tt = 0; tt < 3; tt++) {
            int t = 7 + 2 * tt;
            float g = bg, f = bf, s = bs;
            for (int k = 0; k < 3; k++) {
                int ti = t - 2 + k - 5;
                for (int c = 0; c < 2; c++) {
                    float xv = xs[ti * 2 + c];
                    g += wg[c * 3 + k] * xv;
                    f += wf[c * 3 + k] * xv;
                    s += wsv[c * 3 + k] * xv;
                }
            }
            float gate = 1.f / (1.f + expf(-g));
            float y = gate * f + (1.f - gate) * s;
            float sum, sq;
            block_reduce_sum2(y, y * y, red, sum, sq);
            float mean = sum * (1.f / 256.f);
            float var = sq * (1.f / 256.f) - mean * mean;
            float v = (y - mean) * rsqrtf(var + 1e-5f) * gln + bln;
            v = fmaxf(v, 0.f);
            size_t p = (size_t)node * 768 + tt * 256 + o;
            split_bf(v, Xhi[p], Xlo[p]);
        }
    }
}

// ---------------- split-bf16 MFMA GEMM, double-buffered (BK=32) ----------------
// C(MxN) = A(MxK) @ BT(NxK)^T. 128x128 tile, 4 waves, T3-minimum pipeline.
template<int K, int LDC>
__global__ __launch_bounds__(256, 2) void gemm_split(
    const unsigned short* __restrict__ Ahi, const unsigned short* __restrict__ Alo,
    const unsigned short* __restrict__ BThi, const unsigned short* __restrict__ BTlo,
    float* __restrict__ C) {
    __shared__ __align__(16) unsigned short lAhi[2][128 * 32];
    __shared__ __align__(16) unsigned short lAlo[2][128 * 32];
    __shared__ __align__(16) unsigned short lBhi[2][128 * 32];
    __shared__ __align__(16) unsigned short lBlo[2][128 * 32];
    int tid = threadIdx.x;
    int lane = tid & 63;
    int w = tid >> 6;
    int wr = w >> 1, wc = w & 1;
    int r = lane & 15, g4 = lane >> 4;
    int row0 = blockIdx.y * 128;
    int col0 = blockIdx.x * 128;
    f32x4 acc[4][4] = {};

    // staging: 512 16B-chunks per buffer, 2 per thread
    int c0 = tid, c1 = 256 + tid;
    int tr0 = c0 >> 2, tk0 = (c0 & 3) * 8;
    int tr1 = c1 >> 2, tk1 = (c1 & 3) * 8;

#define STAGE(sel, kk) do { \
    size_t ga0 = (size_t)(row0 + tr0) * K + (kk) + tk0; \
    size_t gb0 = (size_t)(col0 + tr0) * K + (kk) + tk0; \
    size_t ga1 = (size_t)(row0 + tr1) * K + (kk) + tk1; \
    size_t gb1 = (size_t)(col0 + tr1) * K + (kk) + tk1; \
    GLOAD16(Ahi + ga0, &lAhi[sel][c0 * 8]); \
    GLOAD16(Alo + ga0, &lAlo[sel][c0 * 8]); \
    GLOAD16(BThi + gb0, &lBhi[sel][c0 * 8]); \
    GLOAD16(BTlo + gb0, &lBlo[sel][c0 * 8]); \
    GLOAD16(Ahi + ga1, &lAhi[sel][c1 * 8]); \
    GLOAD16(Alo + ga1, &lAlo[sel][c1 * 8]); \
    GLOAD16(BThi + gb1, &lBhi[sel][c1 * 8]); \
    GLOAD16(BTlo + gb1, &lBlo[sel][c1 * 8]); \
} while (0)

    STAGE(0, 0);
    asm volatile("s_waitcnt vmcnt(0)" ::: "memory");
    __syncthreads();

    constexpr int NT = K >> 5;
    #pragma unroll
    for (int t = 0; t < NT; ++t) {
        int cur = t & 1;
        if (t + 1 < NT) STAGE((t + 1) & 1, (t + 1) * 32);
        int ko = g4 * 8;
        short8 ah[4], al[4], bh[4], bl[4];
        #pragma unroll
        for (int mi = 0; mi < 4; ++mi) {
            int rr = (wr * 64 + mi * 16 + r) * 32 + ko;
            ah[mi] = *(const short8*)&lAhi[cur][rr];
            al[mi] = *(const short8*)&lAlo[cur][rr];
        }
        #pragma unroll
        for (int ni = 0; ni < 4; ++ni) {
            int rr = (wc * 64 + ni * 16 + r) * 32 + ko;
            bh[ni] = *(const short8*)&lBhi[cur][rr];
            bl[ni] = *(const short8*)&lBlo[cur][rr];
        }
        #pragma unroll
        for (int mi = 0; mi < 4; ++mi)
            #pragma unroll
            for (int ni = 0; ni < 4; ++ni) {
                acc[mi][ni] = __builtin_amdgcn_mfma_f32_16x16x32_bf16(ah[mi], bh[ni], acc[mi][ni], 0, 0, 0);
                acc[mi][ni] = __builtin_amdgcn_mfma_f32_16x16x32_bf16(ah[mi], bl[ni], acc[mi][ni], 0, 0, 0);
                acc[mi][ni] = __builtin_amdgcn_mfma_f32_16x16x32_bf16(al[mi], bh[ni], acc[mi][ni], 0, 0, 0);
            }
        asm volatile("s_waitcnt vmcnt(0)" ::: "memory");
        __syncthreads();
    }
#undef STAGE

    #pragma unroll
    for (int mi = 0; mi < 4; ++mi) {
        #pragma unroll
        for (int ni = 0; ni < 4; ++ni) {
            int rowb = row0 + wr * 64 + mi * 16 + g4 * 4;
            int colb = col0 + wc * 64 + ni * 16 + r;
            #pragma unroll
            for (int j = 0; j < 4; ++j)
                C[(size_t)(rowb + j) * LDC + colb] = acc[mi][ni][j];
        }
    }
}

// ---------------- layer-1 epilogue -> HLhi/HLlo ----------------
__global__ __launch_bounds__(256) void epi1_kernel(
    const float* __restrict__ Y1, const float* __restrict__ x,
    const float* __restrict__ bg1, const float* __restrict__ bf1, const float* __restrict__ bs1,
    const float* __restrict__ lg, const float* __restrict__ lb,
    const float* __restrict__ wsk, const float* __restrict__ bsk,
    unsigned short* __restrict__ HLhi, unsigned short* __restrict__ HLlo) {
    int node = blockIdx.x, o = threadIdx.x;
    __shared__ float red[8];
    size_t base = (size_t)node * 768;
    float g = Y1[base + o] + bg1[o];
    float f = Y1[base + 256 + o] + bf1[o];
    float s = Y1[base + 512 + o] + bs1[o];
    float gate = 1.f / (1.f + expf(-g));
    float y = gate * f + (1.f - gate) * s;
    float sum, sq;
    block_reduce_sum2(y, y * y, red, sum, sq);
    float mean = sum * (1.f / 256.f);
    float var = sq * (1.f / 256.f) - mean * mean;
    float v = (y - mean) * rsqrtf(var + 1e-5f) * lg[o] + lb[o];
    v = fmaxf(v, 0.f);
    float x0 = x[(size_t)(node * 12 + 11) * 2];
    float x1 = x[(size_t)(node * 12 + 11) * 2 + 1];
    float res = x0 * wsk[o] + x1 * wsk[256 + o] + bsk[o];
    size_t p = (size_t)node * 256 + o;
    split_bf(v + res, HLhi[p], HLlo[p]);
}

// ---------------- fused GAT (fixed + adaptive) -> U ----------------
__global__ __launch_bounds__(256) void gat_kernel(
    const float* __restrict__ Y2, const float* __restrict__ ef,
    const int* __restrict__ fei, const float* __restrict__ AeS,
    const int* __restrict__ cnt, const int* __restrict__ idxs, const float* __restrict__ logv,
    unsigned short* __restrict__ Uhi, unsigned short* __restrict__ Ulo) {
    int tid = threadIdx.x;
    if (blockIdx.x < NODES) {
        // ---- fixed-graph GAT -> U cols [0,256)
        int node = blockIdx.x;
        int b = node / 400, n = node % 400;
        __shared__ int snd[9];
        __shared__ float sv[9][8];
        __shared__ float al[9][8];
        if (tid < 9) snd[tid] = fei[LL + n * 9 + tid];
        __syncthreads();
        if (tid < 72) {
            int j = tid / 8, h = tid % 8;
            int l = n * 9 + j;
            float e0 = ef[((size_t)b * LL + l) * 2];
            float e1 = ef[((size_t)b * LL + l) * 2 + 1];
            float ae = e0 * AeS[h] + e1 * AeS[8 + h];
            float aq = Y2[(size_t)node * 640 + 512 + h];
            float ak = Y2[((size_t)(b * 400 + snd[j])) * 640 + 520 + h];
            float s = aq + ak + ae;
            s = s > 0.f ? s : 0.2f * s;
            sv[j][h] = s;
        }
        __syncthreads();
        if (tid < 8) {
            int h = tid;
            float mx = -1e30f;
            for (int j = 0; j < 9; j++) mx = fmaxf(mx, sv[j][h]);
            float den = 0.f;
            for (int j = 0; j < 9; j++) { float e = expf(sv[j][h] - mx); al[j][h] = e; den += e; }
            den = fmaxf(den, 1e-12f);
            for (int j = 0; j < 9; j++) al[j][h] /= den;
        }
        __syncthreads();
        int h = tid >> 5, d = tid & 31;
        float acc = 0.f;
        for (int j = 0; j < 9; j++)
            acc += al[j][h] * Y2[((size_t)(b * 400 + snd[j])) * 640 + h * 32 + d];
        float e = acc > 0.f ? acc : (expf(acc) - 1.f);
        size_t p = (size_t)node * 512 + tid;
        split_bf(e, Uhi[p], Ulo[p]);
    } else {
        // ---- adaptive attention -> U cols [256,512)
        int node = blockIdx.x - NODES;
        int b = node / 400, n = node % 400;
        __shared__ int jidx[64];
        __shared__ float jlog[64];
        __shared__ float sc[64][8];
        __shared__ float alb[64][8];
        int c = cnt[n];
        if (tid < c) { jidx[tid] = idxs[n * 64 + tid]; jlog[tid] = logv[n * 64 + tid]; }
        __syncthreads();
        for (int e = tid; e < c * 8; e += 256) {
            int j = e / 8, h = e % 8;
            float aq = Y2[(size_t)node * 640 + 528 + h];
            float ak = Y2[((size_t)(b * 400 + jidx[j])) * 640 + 536 + h];
            float s = aq + ak;
            s = s > 0.f ? s : 0.2f * s;
            sc[j][h] = s + jlog[j];
        }
        __syncthreads();
        if (tid < 8) {
            int h = tid; float mx = -1e30f;
            for (int j = 0; j < c; j++) mx = fmaxf(mx, sc[j][h]);
            float den = 0.f;
            for (int j = 0; j < c; j++) { float e = expf(sc[j][h] - mx); alb[j][h] = e; den += e; }
            for (int j = 0; j < c; j++) alb[j][h] /= den;
        }
        __syncthreads();
        int h = tid >> 5, d = tid & 31;
        float acc = 0.f;
        for (int j = 0; j < c; j++)
            acc += alb[j][h] * Y2[((size_t)(b * 400 + jidx[j])) * 640 + 256 + h * 32 + d];
        float e = acc > 0.f ? acc : (expf(acc) - 1.f);
        size_t p = (size_t)node * 512 + 256 + tid;
        split_bf(e, Uhi[p], Ulo[p]);
    }
}

// ---------------- final fuse + output projection ----------------
__global__ __launch_bounds__(256) void final_kernel(
    const float* __restrict__ Y3,
    const float* __restrict__ fb1, const float* __restrict__ fb2, const float* __restrict__ fb3,
    const float* __restrict__ Wo, const float* __restrict__ bo,
    float* __restrict__ out) {
    int node = blockIdx.x, o = threadIdx.x;
    __shared__ float red[12];
    size_t base = (size_t)node * 768;
    float g = 1.f / (1.f + expf(-(Y3[base + o] + fb1[o])));
    float a2 = Y3[base + 256 + o] + fb2[o];
    float a3 = Y3[base + 512 + o] + fb3[o];
    float fused = tanhf(g * a2 + (1.f - g) * a3);
    float v0 = fused * Wo[o * 3 + 0];
    float v1 = fused * Wo[o * 3 + 1];
    float v2 = fused * Wo[o * 3 + 2];
    #pragma unroll
    for (int off = 32; off > 0; off >>= 1) {
        v0 += __shfl_xor(v0, off, 64);
        v1 += __shfl_xor(v1, off, 64);
        v2 += __shfl_xor(v2, off, 64);
    }
    int w = o >> 6, l = o & 63;
    if (l == 0) { red[w] = v0; red[4 + w] = v1; red[8 + w] = v2; }
    __syncthreads();
    if (o < 3) {
        float s = red[o * 4] + red[o * 4 + 1] + red[o * 4 + 2] + red[o * 4 + 3];
        out[(size_t)node * 3 + o] = s + bo[o];
    }
}

// ---------------- launcher ----------------
extern "C" void kernel_launch(void* const* d_in, const int* in_sizes, int n_in,
                              void* d_out, int out_size, void* d_ws, size_t ws_size,
                              hipStream_t stream) {
    const float* x   = (const float*)d_in[0];
    const float* ef  = (const float*)d_in[1];
    const int*   fei = (const int*)d_in[2];
    const float* wg0 = (const float*)d_in[3];
    const float* bg0 = (const float*)d_in[4];
    const float* wf0 = (const float*)d_in[5];
    const float* bf0 = (const float*)d_in[6];
    const float* ws0 = (const float*)d_in[7];
    const float* bs0 = (const float*)d_in[8];
    const float* ln0g = (const float*)d_in[9];
    const float* ln0b = (const float*)d_in[10];
    const float* wg1 = (const float*)d_in[11];
    const float* bg1 = (const float*)d_in[12];
    const float* wf1 = (const float*)d_in[13];
    const float* bf1 = (const float*)d_in[14];
    const float* ws1 = (const float*)d_in[15];
    const float* bs1 = (const float*)d_in[16];
    const float* ln1g = (const float*)d_in[17];
    const float* ln1b = (const float*)d_in[18];
    const float* wsk = (const float*)d_in[19];
    const float* bsk = (const float*)d_in[20];
    const float* sWq = (const float*)d_in[21];
    const float* sWk = (const float*)d_in[22];
    const float* sWv = (const float*)d_in[23];
    const float* sWe = (const float*)d_in[24];
    const float* saq = (const float*)d_in[25];
    const float* sak = (const float*)d_in[26];
    const float* sae = (const float*)d_in[27];
    const float* dWq = (const float*)d_in[28];
    const float* dWk = (const float*)d_in[29];
    const float* dWv = (const float*)d_in[30];
    const float* daq = (const float*)d_in[31];
    const float* dak = (const float*)d_in[32];
    const float* E1  = (const float*)d_in[33];
    const float* E2  = (const float*)d_in[34];
    const float* fW1 = (const float*)d_in[35];
    const float* fb1 = (const float*)d_in[36];
    const float* fW2 = (const float*)d_in[37];
    const float* fb2 = (const float*)d_in[38];
    const float* fW3 = (const float*)d_in[39];
    const float* fb3 = (const float*)d_in[40];
    const float* Wo  = (const float*)d_in[41];
    const float* bo  = (const float*)d_in[42];
    float* out = (float*)d_out;

    char* b = (char*)d_ws;
    unsigned short* Xhi  = (unsigned short*)(b + 0);
    unsigned short* Xlo  = (unsigned short*)(b + 9830400);
    float*          Y1   = (float*)(b + 19660800);
    unsigned short* HLhi = (unsigned short*)(b + 39321600);
    unsigned short* HLlo = (unsigned short*)(b + 42598400);
    unsigned short* Uhi  = (unsigned short*)(b + 45875200);
    unsigned short* Ulo  = (unsigned short*)(b + 52428800);
    unsigned short* W1hi = (unsigned short*)(b + 58982400);
    unsigned short* W1lo = (unsigned short*)(b + 60162048);
    unsigned short* W2hi = (unsigned short*)(b + 61341696);
    unsigned short* W2lo = (unsigned short*)(b + 61669376);
    unsigned short* W3hi = (unsigned short*)(b + 61997056);
    unsigned short* W3lo = (unsigned short*)(b + 62783488);
    float*          AES  = (float*)(b + 63569920);
    float*          LOGV = (float*)(b + 63570176);
    int*            CNT  = (int*)(b + 63672576);
    int*            IDX  = (int*)(b + 63674176);
    float*          Y2   = (float*)(b + 0);
    float*          Y3   = Y1;

    // all input-only work in ONE launch
    prep_kernel<<<10981, 256, 0, stream>>>(
        wg1, wf1, ws1,
        sWv, dWv, sWq, saq, sWk, sak, dWq, daq, dWk, dak,
        fW1, fW2, fW3, sWe, sae, E1, E2,
        x, wg0, bg0, wf0, bf0, ws0, bs0, ln0g, ln0b,
        W1hi, W1lo, W2hi, W2lo, W3hi, W3lo, AES,
        CNT, IDX, LOGV, Xhi, Xlo);

    // G1: Y1 = X @ W1  (M=6400, N=768, K=768)
    gemm_split<768, 768><<<dim3(6, 50), 256, 0, stream>>>(Xhi, Xlo, W1hi, W1lo, Y1);

    epi1_kernel<<<NODES, 256, 0, stream>>>(Y1, x, bg1, bf1, bs1, ln1g, ln1b, wsk, bsk, HLhi, HLlo);

    // G2: Y2 = HL @ W2 (M=6400, N=640, K=256)
    gemm_split<256, 640><<<dim3(5, 50), 256, 0, stream>>>(HLhi, HLlo, W2hi, W2lo, Y2);

    // fused attention stages -> U
    gat_kernel<<<2 * NODES, 256, 0, stream>>>(Y2, ef, fei, AES, CNT, IDX, LOGV, Uhi, Ulo);

    // G3: Y3 = U @ W3 (M=6400, N=768, K=512)
    gemm_split<512, 768><<<dim3(6, 50), 256, 0, stream>>>(Uhi, Ulo, W3hi, W3lo, Y3);

    final_kernel<<<NODES, 256, 0, stream>>>(Y3, fb1, fb2, fb3, Wo, bo, out);
}

// Round 5
// 146.141 us; speedup vs baseline: 4.0186x; 1.1371x over previous
//
#include <hip/hip_runtime.h>
#include <math.h>

// Problem constants
#define LL 3600
#define NODES 6400

typedef __attribute__((ext_vector_type(8))) short short8;
typedef __attribute__((ext_vector_type(4))) float f32x4;

// ---------------- bf16 helpers (manual, RN-even) ----------------
__device__ __forceinline__ unsigned short f2bf(float f) {
    unsigned u = __float_as_uint(f);
    unsigned r = (u + 0x7fffu + ((u >> 16) & 1u)) >> 16;
    return (unsigned short)r;
}
__device__ __forceinline__ float bf2f(unsigned short s) {
    return __uint_as_float(((unsigned)s) << 16);
}
__device__ __forceinline__ void split_bf(float v, unsigned short& hi, unsigned short& lo) {
    hi = f2bf(v);
    lo = f2bf(v - bf2f(hi));
}

#define GLOAD16(gp, lp) __builtin_amdgcn_global_load_lds( \
    (const __attribute__((address_space(1))) unsigned int*)(const void*)(gp), \
    (__attribute__((address_space(3))) unsigned int*)(void*)(lp), 16, 0, 0)

// ---------------- block reduce (wave shuffle + 4-way LDS) ----------------
__device__ __forceinline__ void block_reduce_sum2(float a, float b, float* red, float& ra, float& rb) {
    #pragma unroll
    for (int o = 32; o > 0; o >>= 1) { a += __shfl_xor(a, o, 64); b += __shfl_xor(b, o, 64); }
    int w = threadIdx.x >> 6, l = threadIdx.x & 63;
    if (l == 0) { red[w] = a; red[4 + w] = b; }
    __syncthreads();
    ra = red[0] + red[1] + red[2] + red[3];
    rb = red[4] + red[5] + red[6] + red[7];
    __syncthreads();
}

// ================= MEGA PREP KERNEL =================
// blocks [0,2304): W1T  | [2304,2944): W2T | [2944,4480): W3T
// [4480]: AeS | [4481,4581): adj | [4581,10981): tcn0
__global__ __launch_bounds__(256) void prep_kernel(
    const float* __restrict__ wg1, const float* __restrict__ wf1, const float* __restrict__ ws1,
    const float* __restrict__ sWv, const float* __restrict__ dWv,
    const float* __restrict__ sWq, const float* __restrict__ saq,
    const float* __restrict__ sWk, const float* __restrict__ sak,
    const float* __restrict__ dWq, const float* __restrict__ daq,
    const float* __restrict__ dWk, const float* __restrict__ dak,
    const float* __restrict__ fW1, const float* __restrict__ fW2, const float* __restrict__ fW3,
    const float* __restrict__ sWe, const float* __restrict__ sae,
    const float* __restrict__ E1, const float* __restrict__ E2,
    const float* __restrict__ x,
    const float* __restrict__ wg0, const float* __restrict__ bg0,
    const float* __restrict__ wf0, const float* __restrict__ bf0,
    const float* __restrict__ ws0, const float* __restrict__ bs0,
    const float* __restrict__ lg0, const float* __restrict__ lb0,
    unsigned short* __restrict__ W1hi, unsigned short* __restrict__ W1lo,
    unsigned short* __restrict__ W2hi, unsigned short* __restrict__ W2lo,
    unsigned short* __restrict__ W3hi, unsigned short* __restrict__ W3lo,
    float* __restrict__ AeS,
    int* __restrict__ cnt, int* __restrict__ idxs, float* __restrict__ logv,
    unsigned short* __restrict__ Xhi, unsigned short* __restrict__ Xlo) {
    __shared__ float smem[22];   // tcn0: xs[14] + red[8]
    int bid = blockIdx.x;
    int tid = threadIdx.x;

    if (bid < 2304) {
        // ---- W1T[n][k]: n = which*256+o, k = tt*256+i; val = w1[o][i][tt]
        int idx = bid * 256 + tid;
        int n = idx / 768, k = idx % 768;
        int which = n >> 8, o = n & 255;
        int tt = k >> 8, i = k & 255;
        const float* w = which == 0 ? wg1 : (which == 1 ? wf1 : ws1);
        float v = w[(o * 256 + i) * 3 + tt];
        split_bf(v, W1hi[idx], W1lo[idx]);
    } else if (bid < 2944) {
        // ---- W2T[n][k], n in [0,640), k in [0,256)
        int idx = (bid - 2304) * 256 + tid;
        int n = idx / 256, k = idx % 256;
        float v = 0.f;
        if (n < 256) v = sWv[k * 256 + n];
        else if (n < 512) v = dWv[k * 256 + (n - 256)];
        else if (n < 544) {
            int j = n - 512, g = j >> 3, h = j & 7;
            const float* Wm = g == 0 ? sWq : (g == 1 ? sWk : (g == 2 ? dWq : dWk));
            const float* am = g == 0 ? saq : (g == 1 ? sak : (g == 2 ? daq : dak));
            float s = 0.f;
            for (int d = 0; d < 32; d++) s += Wm[k * 256 + h * 32 + d] * am[h * 32 + d];
            v = s;
        }
        split_bf(v, W2hi[idx], W2lo[idx]);
    } else if (bid < 4480) {
        // ---- W3T[n][k], n in [0,768), k in [0,512)
        int idx = (bid - 2944) * 256 + tid;
        int n = idx / 512, k = idx % 512;
        float v = 0.f;
        if (k < 256) {
            if (n < 256) v = fW1[k * 256 + n];
            else if (n < 512) v = fW2[k * 256 + (n - 256)];
        } else {
            int c = k - 256;
            if (n < 256) v = fW1[c * 256 + n];
            else if (n >= 512) v = fW3[c * 256 + (n - 512)];
        }
        split_bf(v, W3hi[idx], W3lo[idx]);
    } else if (bid == 4480) {
        if (tid < 16) {
            int cc = tid / 8, h = tid % 8;
            float s = 0.f;
            for (int d = 0; d < 32; d++) s += sWe[cc * 256 + h * 32 + d] * sae[h * 32 + d];
            AeS[tid] = s;
        }
    } else if (bid < 4581) {
        // ---- adjacency: one wave per row
        int n = ((bid - 4481) * 256 + tid) >> 6;
        int lane = tid & 63;
        if (n >= 400) return;
        float e1[10];
        #pragma unroll
        for (int k = 0; k < 10; k++) e1[k] = E1[n * 10 + k];
        float p[7];
        #pragma unroll
        for (int i = 0; i < 7; i++) {
            int j = i * 64 + lane;
            if (j < 400) {
                float s = 0.f;
                #pragma unroll
                for (int k = 0; k < 10; k++) s += e1[k] * E2[j * 10 + k];
                p[i] = fmaxf(s, 0.f);
            } else p[i] = -1e30f;
        }
        float mx = -1e30f;
        #pragma unroll
        for (int i = 0; i < 7; i++) mx = fmaxf(mx, p[i]);
        #pragma unroll
        for (int o = 32; o > 0; o >>= 1) mx = fmaxf(mx, __shfl_xor(mx, o, 64));
        float sum = 0.f;
        #pragma unroll
        for (int i = 0; i < 7; i++) {
            int j = i * 64 + lane;
            if (j < 400) { p[i] = expf(p[i] - mx); sum += p[i]; }
        }
        #pragma unroll
        for (int o = 32; o > 0; o >>= 1) sum += __shfl_xor(sum, o, 64);
        float inv = 1.f / sum;
        float m[7];
        #pragma unroll
        for (int i = 0; i < 7; i++) {
            int j = i * 64 + lane;
            if (j < 400) { p[i] *= inv; m[i] = p[i]; }
            else m[i] = -1e30f;
        }
        for (int it = 0; it < 15; ++it) {
            float lm = m[0];
            #pragma unroll
            for (int i = 1; i < 7; i++) lm = fmaxf(lm, m[i]);
            float gm = lm;
            #pragma unroll
            for (int o = 32; o > 0; o >>= 1) gm = fmaxf(gm, __shfl_xor(gm, o, 64));
            unsigned long long msk = __ballot(lm == gm);
            int first = (int)(__ffsll((long long)msk)) - 1;
            if (lane == first) {
                #pragma unroll
                for (int i = 0; i < 7; i++) {
                    if (m[i] == gm) { m[i] = -1e30f; break; }
                }
            }
        }
        float kth = m[0];
        #pragma unroll
        for (int i = 1; i < 7; i++) kth = fmaxf(kth, m[i]);
        #pragma unroll
        for (int o = 32; o > 0; o >>= 1) kth = fmaxf(kth, __shfl_xor(kth, o, 64));
        int base = 0;
        #pragma unroll
        for (int i = 0; i < 7; i++) {
            int j = i * 64 + lane;
            bool pred = (j < 400) && (p[i] >= kth);
            unsigned long long msk = __ballot(pred);
            int pre = __popcll(msk & ((lane == 63) ? 0x7fffffffffffffffull : ((1ull << lane) - 1)));
            if (pred) {
                int pos = base + pre;
                if (pos < 64) {
                    idxs[n * 64 + pos] = j;
                    logv[n * 64 + pos] = logf(fmaxf(p[i], 1e-12f));
                }
            }
            base += __popcll(msk);
        }
        if (lane == 0) cnt[n] = base < 64 ? base : 64;
    } else {
        // ---- TCN layer 0
        int node = bid - 4581;
        int o = tid;
        float* xs = smem;        // [7][2]
        float* red = smem + 14;  // [8]
        if (o < 14) { int t = 5 + o / 2, c = o & 1; xs[(t - 5) * 2 + c] = x[(size_t)(node * 12 + t) * 2 + c]; }
        __syncthreads();
        float wg[6], wf[6], wsv[6];
        for (int i = 0; i < 6; i++) { wg[i] = wg0[o * 6 + i]; wf[i] = wf0[o * 6 + i]; wsv[i] = ws0[o * 6 + i]; }
        float bg = bg0[o], bf = bf0[o], bs = bs0[o];
        float gln = lg0[o], bln = lb0[o];
        for (int tt = 0; tt < 3; tt++) {
            int t = 7 + 2 * tt;
            float g = bg, f = bf, s = bs;
            for (int k = 0; k < 3; k++) {
                int ti = t - 2 + k - 5;
                for (int c = 0; c < 2; c++) {
                    float xv = xs[ti * 2 + c];
                    g += wg[c * 3 + k] * xv;
                    f += wf[c * 3 + k] * xv;
                    s += wsv[c * 3 + k] * xv;
                }
            }
            float gate = 1.f / (1.f + expf(-g));
            float y = gate * f + (1.f - gate) * s;
            float sum, sq;
            block_reduce_sum2(y, y * y, red, sum, sq);
            float mean = sum * (1.f / 256.f);
            float var = sq * (1.f / 256.f) - mean * mean;
            float v = (y - mean) * rsqrtf(var + 1e-5f) * gln + bln;
            v = fmaxf(v, 0.f);
            size_t p = (size_t)node * 768 + tt * 256 + o;
            split_bf(v, Xhi[p], Xlo[p]);
        }
    }
}

// ---------------- split-bf16 MFMA GEMM, 64x128 tile, BK=32, double-buffered ----------------
// C(MxN) = A(MxK) @ BT(NxK)^T. Grid: GX col-blocks x 100 row-blocks, bijective XCD swizzle.
// 4 waves as 2x2; each wave 32x64 (2x4 16x16 frags), 3 MFMA terms per frag.
template<int K, int LDC, int GX>
__global__ __launch_bounds__(256, 3) void gemm_split(
    const unsigned short* __restrict__ Ahi, const unsigned short* __restrict__ Alo,
    const unsigned short* __restrict__ BThi, const unsigned short* __restrict__ BTlo,
    float* __restrict__ C) {
    __shared__ __align__(16) unsigned short lA[2][2][64 * 32];    // [buf][hi/lo] 8KB each pair
    __shared__ __align__(16) unsigned short lB[2][2][128 * 32];   // 48KB total
    int tid = threadIdx.x;
    int lane = tid & 63;
    int w = tid >> 6;
    int wm = w >> 1, wn = w & 1;
    int r = lane & 15, g4 = lane >> 4;
    int ko = g4 * 8;

    // bijective XCD swizzle (m204)
    constexpr int NWG = GX * 100;
    constexpr int Q = NWG / 8, R = NWG % 8;
    int flat = blockIdx.y * GX + blockIdx.x;
    int xcd = flat & 7, idx = flat >> 3;
    int nf = (xcd < R ? xcd * (Q + 1) : R * (Q + 1) + (xcd - R) * Q) + idx;
    int col0 = (nf % GX) * 128;
    int row0 = (nf / GX) * 64;

    f32x4 acc[2][4] = {};

    // staging geometry: A = 256 chunks (1/thread), B = 512 chunks (2/thread)
    int rA = tid >> 2;            // 0..63
    int kA = (tid & 3) * 8;       // shorts
    int rB1 = 64 + (tid >> 2);

#define STAGE(sel, kk) do { \
    GLOAD16(Ahi + (size_t)(row0 + rA) * K + (kk) + kA, &lA[sel][0][tid * 8]); \
    GLOAD16(Alo + (size_t)(row0 + rA) * K + (kk) + kA, &lA[sel][1][tid * 8]); \
    GLOAD16(BThi + (size_t)(col0 + rA) * K + (kk) + kA, &lB[sel][0][tid * 8]); \
    GLOAD16(BTlo + (size_t)(col0 + rA) * K + (kk) + kA, &lB[sel][1][tid * 8]); \
    GLOAD16(BThi + (size_t)(col0 + rB1) * K + (kk) + kA, &lB[sel][0][(tid + 256) * 8]); \
    GLOAD16(BTlo + (size_t)(col0 + rB1) * K + (kk) + kA, &lB[sel][1][(tid + 256) * 8]); \
} while (0)

    STAGE(0, 0);
    asm volatile("s_waitcnt vmcnt(0)" ::: "memory");
    __syncthreads();

    constexpr int NT = K >> 5;
    #pragma unroll 2
    for (int t = 0; t < NT; ++t) {
        int cur = t & 1;
        if (t + 1 < NT) STAGE((t + 1) & 1, (t + 1) * 32);
        short8 ah[2], al[2], bh[4], bl[4];
        #pragma unroll
        for (int mi = 0; mi < 2; ++mi) {
            int rr = (wm * 32 + mi * 16 + r) * 32 + ko;
            ah[mi] = *(const short8*)&lA[cur][0][rr];
            al[mi] = *(const short8*)&lA[cur][1][rr];
        }
        #pragma unroll
        for (int ni = 0; ni < 4; ++ni) {
            int rr = (wn * 64 + ni * 16 + r) * 32 + ko;
            bh[ni] = *(const short8*)&lB[cur][0][rr];
            bl[ni] = *(const short8*)&lB[cur][1][rr];
        }
        #pragma unroll
        for (int mi = 0; mi < 2; ++mi)
            #pragma unroll
            for (int ni = 0; ni < 4; ++ni) {
                acc[mi][ni] = __builtin_amdgcn_mfma_f32_16x16x32_bf16(ah[mi], bh[ni], acc[mi][ni], 0, 0, 0);
                acc[mi][ni] = __builtin_amdgcn_mfma_f32_16x16x32_bf16(ah[mi], bl[ni], acc[mi][ni], 0, 0, 0);
                acc[mi][ni] = __builtin_amdgcn_mfma_f32_16x16x32_bf16(al[mi], bh[ni], acc[mi][ni], 0, 0, 0);
            }
        asm volatile("s_waitcnt vmcnt(0)" ::: "memory");
        __syncthreads();
    }
#undef STAGE

    #pragma unroll
    for (int mi = 0; mi < 2; ++mi) {
        #pragma unroll
        for (int ni = 0; ni < 4; ++ni) {
            int rowb = row0 + wm * 32 + mi * 16 + g4 * 4;
            int colb = col0 + wn * 64 + ni * 16 + r;
            #pragma unroll
            for (int j = 0; j < 4; ++j)
                C[(size_t)(rowb + j) * LDC + colb] = acc[mi][ni][j];
        }
    }
}

// ---------------- layer-1 epilogue -> HLhi/HLlo ----------------
__global__ __launch_bounds__(256) void epi1_kernel(
    const float* __restrict__ Y1, const float* __restrict__ x,
    const float* __restrict__ bg1, const float* __restrict__ bf1, const float* __restrict__ bs1,
    const float* __restrict__ lg, const float* __restrict__ lb,
    const float* __restrict__ wsk, const float* __restrict__ bsk,
    unsigned short* __restrict__ HLhi, unsigned short* __restrict__ HLlo) {
    int node = blockIdx.x, o = threadIdx.x;
    __shared__ float red[8];
    size_t base = (size_t)node * 768;
    float g = Y1[base + o] + bg1[o];
    float f = Y1[base + 256 + o] + bf1[o];
    float s = Y1[base + 512 + o] + bs1[o];
    float gate = 1.f / (1.f + expf(-g));
    float y = gate * f + (1.f - gate) * s;
    float sum, sq;
    block_reduce_sum2(y, y * y, red, sum, sq);
    float mean = sum * (1.f / 256.f);
    float var = sq * (1.f / 256.f) - mean * mean;
    float v = (y - mean) * rsqrtf(var + 1e-5f) * lg[o] + lb[o];
    v = fmaxf(v, 0.f);
    float x0 = x[(size_t)(node * 12 + 11) * 2];
    float x1 = x[(size_t)(node * 12 + 11) * 2 + 1];
    float res = x0 * wsk[o] + x1 * wsk[256 + o] + bsk[o];
    size_t p = (size_t)node * 256 + o;
    split_bf(v + res, HLhi[p], HLlo[p]);
}

// ---------------- fused GAT (fixed + adaptive) -> U ----------------
__global__ __launch_bounds__(256) void gat_kernel(
    const float* __restrict__ Y2, const float* __restrict__ ef,
    const int* __restrict__ fei, const float* __restrict__ AeS,
    const int* __restrict__ cnt, const int* __restrict__ idxs, const float* __restrict__ logv,
    unsigned short* __restrict__ Uhi, unsigned short* __restrict__ Ulo) {
    int tid = threadIdx.x;
    if (blockIdx.x < NODES) {
        // ---- fixed-graph GAT -> U cols [0,256)
        int node = blockIdx.x;
        int b = node / 400, n = node % 400;
        __shared__ int snd[9];
        __shared__ float sv[9][8];
        __shared__ float al[9][8];
        if (tid < 9) snd[tid] = fei[LL + n * 9 + tid];
        __syncthreads();
        if (tid < 72) {
            int j = tid / 8, h = tid % 8;
            int l = n * 9 + j;
            float e0 = ef[((size_t)b * LL + l) * 2];
            float e1 = ef[((size_t)b * LL + l) * 2 + 1];
            float ae = e0 * AeS[h] + e1 * AeS[8 + h];
            float aq = Y2[(size_t)node * 640 + 512 + h];
            float ak = Y2[((size_t)(b * 400 + snd[j])) * 640 + 520 + h];
            float s = aq + ak + ae;
            s = s > 0.f ? s : 0.2f * s;
            sv[j][h] = s;
        }
        __syncthreads();
        if (tid < 8) {
            int h = tid;
            float mx = -1e30f;
            for (int j = 0; j < 9; j++) mx = fmaxf(mx, sv[j][h]);
            float den = 0.f;
            for (int j = 0; j < 9; j++) { float e = expf(sv[j][h] - mx); al[j][h] = e; den += e; }
            den = fmaxf(den, 1e-12f);
            for (int j = 0; j < 9; j++) al[j][h] /= den;
        }
        __syncthreads();
        int h = tid >> 5, d = tid & 31;
        float acc = 0.f;
        for (int j = 0; j < 9; j++)
            acc += al[j][h] * Y2[((size_t)(b * 400 + snd[j])) * 640 + h * 32 + d];
        float e = acc > 0.f ? acc : (expf(acc) - 1.f);
        size_t p = (size_t)node * 512 + tid;
        split_bf(e, Uhi[p], Ulo[p]);
    } else {
        // ---- adaptive attention -> U cols [256,512)
        int node = blockIdx.x - NODES;
        int b = node / 400, n = node % 400;
        __shared__ int jidx[64];
        __shared__ float jlog[64];
        __shared__ float sc[64][8];
        __shared__ float alb[64][8];
        int c = cnt[n];
        if (tid < c) { jidx[tid] = idxs[n * 64 + tid]; jlog[tid] = logv[n * 64 + tid]; }
        __syncthreads();
        for (int e = tid; e < c * 8; e += 256) {
            int j = e / 8, h = e % 8;
            float aq = Y2[(size_t)node * 640 + 528 + h];
            float ak = Y2[((size_t)(b * 400 + jidx[j])) * 640 + 536 + h];
            float s = aq + ak;
            s = s > 0.f ? s : 0.2f * s;
            sc[j][h] = s + jlog[j];
        }
        __syncthreads();
        if (tid < 8) {
            int h = tid; float mx = -1e30f;
            for (int j = 0; j < c; j++) mx = fmaxf(mx, sc[j][h]);
            float den = 0.f;
            for (int j = 0; j < c; j++) { float e = expf(sc[j][h] - mx); alb[j][h] = e; den += e; }
            for (int j = 0; j < c; j++) alb[j][h] /= den;
        }
        __syncthreads();
        int h = tid >> 5, d = tid & 31;
        float acc = 0.f;
        for (int j = 0; j < c; j++)
            acc += alb[j][h] * Y2[((size_t)(b * 400 + jidx[j])) * 640 + 256 + h * 32 + d];
        float e = acc > 0.f ? acc : (expf(acc) - 1.f);
        size_t p = (size_t)node * 512 + 256 + tid;
        split_bf(e, Uhi[p], Ulo[p]);
    }
}

// ---------------- final fuse + output projection ----------------
__global__ __launch_bounds__(256) void final_kernel(
    const float* __restrict__ Y3,
    const float* __restrict__ fb1, const float* __restrict__ fb2, const float* __restrict__ fb3,
    const float* __restrict__ Wo, const float* __restrict__ bo,
    float* __restrict__ out) {
    int node = blockIdx.x, o = threadIdx.x;
    __shared__ float red[12];
    size_t base = (size_t)node * 768;
    float g = 1.f / (1.f + expf(-(Y3[base + o] + fb1[o])));
    float a2 = Y3[base + 256 + o] + fb2[o];
    float a3 = Y3[base + 512 + o] + fb3[o];
    float fused = tanhf(g * a2 + (1.f - g) * a3);
    float v0 = fused * Wo[o * 3 + 0];
    float v1 = fused * Wo[o * 3 + 1];
    float v2 = fused * Wo[o * 3 + 2];
    #pragma unroll
    for (int off = 32; off > 0; off >>= 1) {
        v0 += __shfl_xor(v0, off, 64);
        v1 += __shfl_xor(v1, off, 64);
        v2 += __shfl_xor(v2, off, 64);
    }
    int w = o >> 6, l = o & 63;
    if (l == 0) { red[w] = v0; red[4 + w] = v1; red[8 + w] = v2; }
    __syncthreads();
    if (o < 3) {
        float s = red[o * 4] + red[o * 4 + 1] + red[o * 4 + 2] + red[o * 4 + 3];
        out[(size_t)node * 3 + o] = s + bo[o];
    }
}

// ---------------- launcher ----------------
extern "C" void kernel_launch(void* const* d_in, const int* in_sizes, int n_in,
                              void* d_out, int out_size, void* d_ws, size_t ws_size,
                              hipStream_t stream) {
    const float* x   = (const float*)d_in[0];
    const float* ef  = (const float*)d_in[1];
    const int*   fei = (const int*)d_in[2];
    const float* wg0 = (const float*)d_in[3];
    const float* bg0 = (const float*)d_in[4];
    const float* wf0 = (const float*)d_in[5];
    const float* bf0 = (const float*)d_in[6];
    const float* ws0 = (const float*)d_in[7];
    const float* bs0 = (const float*)d_in[8];
    const float* ln0g = (const float*)d_in[9];
    const float* ln0b = (const float*)d_in[10];
    const float* wg1 = (const float*)d_in[11];
    const float* bg1 = (const float*)d_in[12];
    const float* wf1 = (const float*)d_in[13];
    const float* bf1 = (const float*)d_in[14];
    const float* ws1 = (const float*)d_in[15];
    const float* bs1 = (const float*)d_in[16];
    const float* ln1g = (const float*)d_in[17];
    const float* ln1b = (const float*)d_in[18];
    const float* wsk = (const float*)d_in[19];
    const float* bsk = (const float*)d_in[20];
    const float* sWq = (const float*)d_in[21];
    const float* sWk = (const float*)d_in[22];
    const float* sWv = (const float*)d_in[23];
    const float* sWe = (const float*)d_in[24];
    const float* saq = (const float*)d_in[25];
    const float* sak = (const float*)d_in[26];
    const float* sae = (const float*)d_in[27];
    const float* dWq = (const float*)d_in[28];
    const float* dWk = (const float*)d_in[29];
    const float* dWv = (const float*)d_in[30];
    const float* daq = (const float*)d_in[31];
    const float* dak = (const float*)d_in[32];
    const float* E1  = (const float*)d_in[33];
    const float* E2  = (const float*)d_in[34];
    const float* fW1 = (const float*)d_in[35];
    const float* fb1 = (const float*)d_in[36];
    const float* fW2 = (const float*)d_in[37];
    const float* fb2 = (const float*)d_in[38];
    const float* fW3 = (const float*)d_in[39];
    const float* fb3 = (const float*)d_in[40];
    const float* Wo  = (const float*)d_in[41];
    const float* bo  = (const float*)d_in[42];
    float* out = (float*)d_out;

    char* b = (char*)d_ws;
    unsigned short* Xhi  = (unsigned short*)(b + 0);
    unsigned short* Xlo  = (unsigned short*)(b + 9830400);
    float*          Y1   = (float*)(b + 19660800);
    unsigned short* HLhi = (unsigned short*)(b + 39321600);
    unsigned short* HLlo = (unsigned short*)(b + 42598400);
    unsigned short* Uhi  = (unsigned short*)(b + 45875200);
    unsigned short* Ulo  = (unsigned short*)(b + 52428800);
    unsigned short* W1hi = (unsigned short*)(b + 58982400);
    unsigned short* W1lo = (unsigned short*)(b + 60162048);
    unsigned short* W2hi = (unsigned short*)(b + 61341696);
    unsigned short* W2lo = (unsigned short*)(b + 61669376);
    unsigned short* W3hi = (unsigned short*)(b + 61997056);
    unsigned short* W3lo = (unsigned short*)(b + 62783488);
    float*          AES  = (float*)(b + 63569920);
    float*          LOGV = (float*)(b + 63570176);
    int*            CNT  = (int*)(b + 63672576);
    int*            IDX  = (int*)(b + 63674176);
    float*          Y2   = (float*)(b + 0);
    float*          Y3   = Y1;

    // all input-only work in ONE launch
    prep_kernel<<<10981, 256, 0, stream>>>(
        wg1, wf1, ws1,
        sWv, dWv, sWq, saq, sWk, sak, dWq, daq, dWk, dak,
        fW1, fW2, fW3, sWe, sae, E1, E2,
        x, wg0, bg0, wf0, bf0, ws0, bs0, ln0g, ln0b,
        W1hi, W1lo, W2hi, W2lo, W3hi, W3lo, AES,
        CNT, IDX, LOGV, Xhi, Xlo);

    // G1: Y1 = X @ W1  (M=6400, N=768, K=768)
    gemm_split<768, 768, 6><<<dim3(6, 100), 256, 0, stream>>>(Xhi, Xlo, W1hi, W1lo, Y1);

    epi1_kernel<<<NODES, 256, 0, stream>>>(Y1, x, bg1, bf1, bs1, ln1g, ln1b, wsk, bsk, HLhi, HLlo);

    // G2: Y2 = HL @ W2 (M=6400, N=640, K=256)
    gemm_split<256, 640, 5><<<dim3(5, 100), 256, 0, stream>>>(HLhi, HLlo, W2hi, W2lo, Y2);

    // fused attention stages -> U
    gat_kernel<<<2 * NODES, 256, 0, stream>>>(Y2, ef, fei, AES, CNT, IDX, LOGV, Uhi, Ulo);

    // G3: Y3 = U @ W3 (M=6400, N=768, K=512)
    gemm_split<512, 768, 6><<<dim3(6, 100), 256, 0, stream>>>(Uhi, Ulo, W3hi, W3lo, Y3);

    final_kernel<<<NODES, 256, 0, stream>>>(Y3, fb1, fb2, fb3, Wo, bo, out);
}

// Round 6
// 123.430 us; speedup vs baseline: 4.7580x; 1.1840x over previous
//
#include <hip/hip_runtime.h>
#include <math.h>

// Problem constants
#define LL 3600
#define NODES 6400

typedef __attribute__((ext_vector_type(8))) _Float16 half8;
typedef __attribute__((ext_vector_type(4))) float f32x4;

// ---------------- fp16 helper ----------------
__device__ __forceinline__ unsigned short f2h(float f) {
    union { _Float16 h; unsigned short u; } cv;
    cv.h = (_Float16)f;
    return cv.u;
}

#define GLOAD16(gp, lp) __builtin_amdgcn_global_load_lds( \
    (const __attribute__((address_space(1))) unsigned int*)(const void*)(gp), \
    (__attribute__((address_space(3))) unsigned int*)(void*)(lp), 16, 0, 0)

// ---------------- block reduce (wave shuffle + 4-way LDS) ----------------
__device__ __forceinline__ void block_reduce_sum2(float a, float b, float* red, float& ra, float& rb) {
    #pragma unroll
    for (int o = 32; o > 0; o >>= 1) { a += __shfl_xor(a, o, 64); b += __shfl_xor(b, o, 64); }
    int w = threadIdx.x >> 6, l = threadIdx.x & 63;
    if (l == 0) { red[w] = a; red[4 + w] = b; }
    __syncthreads();
    ra = red[0] + red[1] + red[2] + red[3];
    rb = red[4] + red[5] + red[6] + red[7];
    __syncthreads();
}

// ================= MEGA PREP KERNEL =================
// blocks [0,2304): W1T  | [2304,2944): W2T | [2944,4480): W3T
// [4480]: AeS | [4481,4581): adj | [4581,10981): tcn0
__global__ __launch_bounds__(256) void prep_kernel(
    const float* __restrict__ wg1, const float* __restrict__ wf1, const float* __restrict__ ws1,
    const float* __restrict__ sWv, const float* __restrict__ dWv,
    const float* __restrict__ sWq, const float* __restrict__ saq,
    const float* __restrict__ sWk, const float* __restrict__ sak,
    const float* __restrict__ dWq, const float* __restrict__ daq,
    const float* __restrict__ dWk, const float* __restrict__ dak,
    const float* __restrict__ fW1, const float* __restrict__ fW2, const float* __restrict__ fW3,
    const float* __restrict__ sWe, const float* __restrict__ sae,
    const float* __restrict__ E1, const float* __restrict__ E2,
    const float* __restrict__ x,
    const float* __restrict__ wg0, const float* __restrict__ bg0,
    const float* __restrict__ wf0, const float* __restrict__ bf0,
    const float* __restrict__ ws0, const float* __restrict__ bs0,
    const float* __restrict__ lg0, const float* __restrict__ lb0,
    unsigned short* __restrict__ W1h,
    unsigned short* __restrict__ W2h,
    unsigned short* __restrict__ W3h,
    float* __restrict__ AeS,
    int* __restrict__ cnt, int* __restrict__ idxs, float* __restrict__ logv,
    unsigned short* __restrict__ Xh) {
    __shared__ float smem[22];   // tcn0: xs[14] + red[8]
    int bid = blockIdx.x;
    int tid = threadIdx.x;

    if (bid < 2304) {
        // ---- W1T[n][k]: n = which*256+o, k = tt*256+i; val = w1[o][i][tt]
        int idx = bid * 256 + tid;
        int n = idx / 768, k = idx % 768;
        int which = n >> 8, o = n & 255;
        int tt = k >> 8, i = k & 255;
        const float* w = which == 0 ? wg1 : (which == 1 ? wf1 : ws1);
        W1h[idx] = f2h(w[(o * 256 + i) * 3 + tt]);
    } else if (bid < 2944) {
        // ---- W2T[n][k], n in [0,640), k in [0,256)
        int idx = (bid - 2304) * 256 + tid;
        int n = idx / 256, k = idx % 256;
        float v = 0.f;
        if (n < 256) v = sWv[k * 256 + n];
        else if (n < 512) v = dWv[k * 256 + (n - 256)];
        else if (n < 544) {
            int j = n - 512, g = j >> 3, h = j & 7;
            const float* Wm = g == 0 ? sWq : (g == 1 ? sWk : (g == 2 ? dWq : dWk));
            const float* am = g == 0 ? saq : (g == 1 ? sak : (g == 2 ? daq : dak));
            float s = 0.f;
            for (int d = 0; d < 32; d++) s += Wm[k * 256 + h * 32 + d] * am[h * 32 + d];
            v = s;
        }
        W2h[idx] = f2h(v);
    } else if (bid < 4480) {
        // ---- W3T[n][k], n in [0,768), k in [0,512)
        int idx = (bid - 2944) * 256 + tid;
        int n = idx / 512, k = idx % 512;
        float v = 0.f;
        if (k < 256) {
            if (n < 256) v = fW1[k * 256 + n];
            else if (n < 512) v = fW2[k * 256 + (n - 256)];
        } else {
            int c = k - 256;
            if (n < 256) v = fW1[c * 256 + n];
            else if (n >= 512) v = fW3[c * 256 + (n - 512)];
        }
        W3h[idx] = f2h(v);
    } else if (bid == 4480) {
        if (tid < 16) {
            int cc = tid / 8, h = tid % 8;
            float s = 0.f;
            for (int d = 0; d < 32; d++) s += sWe[cc * 256 + h * 32 + d] * sae[h * 32 + d];
            AeS[tid] = s;
        }
    } else if (bid < 4581) {
        // ---- adjacency: one wave per row
        int n = ((bid - 4481) * 256 + tid) >> 6;
        int lane = tid & 63;
        if (n >= 400) return;
        float e1[10];
        #pragma unroll
        for (int k = 0; k < 10; k++) e1[k] = E1[n * 10 + k];
        float p[7];
        #pragma unroll
        for (int i = 0; i < 7; i++) {
            int j = i * 64 + lane;
            if (j < 400) {
                float s = 0.f;
                #pragma unroll
                for (int k = 0; k < 10; k++) s += e1[k] * E2[j * 10 + k];
                p[i] = fmaxf(s, 0.f);
            } else p[i] = -1e30f;
        }
        float mx = -1e30f;
        #pragma unroll
        for (int i = 0; i < 7; i++) mx = fmaxf(mx, p[i]);
        #pragma unroll
        for (int o = 32; o > 0; o >>= 1) mx = fmaxf(mx, __shfl_xor(mx, o, 64));
        float sum = 0.f;
        #pragma unroll
        for (int i = 0; i < 7; i++) {
            int j = i * 64 + lane;
            if (j < 400) { p[i] = expf(p[i] - mx); sum += p[i]; }
        }
        #pragma unroll
        for (int o = 32; o > 0; o >>= 1) sum += __shfl_xor(sum, o, 64);
        float inv = 1.f / sum;
        float m[7];
        #pragma unroll
        for (int i = 0; i < 7; i++) {
            int j = i * 64 + lane;
            if (j < 400) { p[i] *= inv; m[i] = p[i]; }
            else m[i] = -1e30f;
        }
        for (int it = 0; it < 15; ++it) {
            float lm = m[0];
            #pragma unroll
            for (int i = 1; i < 7; i++) lm = fmaxf(lm, m[i]);
            float gm = lm;
            #pragma unroll
            for (int o = 32; o > 0; o >>= 1) gm = fmaxf(gm, __shfl_xor(gm, o, 64));
            unsigned long long msk = __ballot(lm == gm);
            int first = (int)(__ffsll((long long)msk)) - 1;
            if (lane == first) {
                #pragma unroll
                for (int i = 0; i < 7; i++) {
                    if (m[i] == gm) { m[i] = -1e30f; break; }
                }
            }
        }
        float kth = m[0];
        #pragma unroll
        for (int i = 1; i < 7; i++) kth = fmaxf(kth, m[i]);
        #pragma unroll
        for (int o = 32; o > 0; o >>= 1) kth = fmaxf(kth, __shfl_xor(kth, o, 64));
        int base = 0;
        #pragma unroll
        for (int i = 0; i < 7; i++) {
            int j = i * 64 + lane;
            bool pred = (j < 400) && (p[i] >= kth);
            unsigned long long msk = __ballot(pred);
            int pre = __popcll(msk & ((lane == 63) ? 0x7fffffffffffffffull : ((1ull << lane) - 1)));
            if (pred) {
                int pos = base + pre;
                if (pos < 64) {
                    idxs[n * 64 + pos] = j;
                    logv[n * 64 + pos] = logf(fmaxf(p[i], 1e-12f));
                }
            }
            base += __popcll(msk);
        }
        if (lane == 0) cnt[n] = base < 64 ? base : 64;
    } else {
        // ---- TCN layer 0
        int node = bid - 4581;
        int o = tid;
        float* xs = smem;        // [7][2]
        float* red = smem + 14;  // [8]
        if (o < 14) { int t = 5 + o / 2, c = o & 1; xs[(t - 5) * 2 + c] = x[(size_t)(node * 12 + t) * 2 + c]; }
        __syncthreads();
        float wg[6], wf[6], wsv[6];
        for (int i = 0; i < 6; i++) { wg[i] = wg0[o * 6 + i]; wf[i] = wf0[o * 6 + i]; wsv[i] = ws0[o * 6 + i]; }
        float bg = bg0[o], bf = bf0[o], bs = bs0[o];
        float gln = lg0[o], bln = lb0[o];
        for (int tt = 0; tt < 3; tt++) {
            int t = 7 + 2 * tt;
            float g = bg, f = bf, s = bs;
            for (int k = 0; k < 3; k++) {
                int ti = t - 2 + k - 5;
                for (int c = 0; c < 2; c++) {
                    float xv = xs[ti * 2 + c];
                    g += wg[c * 3 + k] * xv;
                    f += wf[c * 3 + k] * xv;
                    s += wsv[c * 3 + k] * xv;
                }
            }
            float gate = 1.f / (1.f + expf(-g));
            float y = gate * f + (1.f - gate) * s;
            float sum, sq;
            block_reduce_sum2(y, y * y, red, sum, sq);
            float mean = sum * (1.f / 256.f);
            float var = sq * (1.f / 256.f) - mean * mean;
            float v = (y - mean) * rsqrtf(var + 1e-5f) * gln + bln;
            v = fmaxf(v, 0.f);
            Xh[(size_t)node * 768 + tt * 256 + o] = f2h(v);
        }
    }
}

// ---------------- fp16 MFMA GEMM, 64x128 tile, BK=32, double-buffered, LDS-swizzled ----------------
// C(MxN) = A(MxK) @ BT(NxK)^T. Grid: GX col-blocks x 100 row-blocks, bijective XCD swizzle.
// 4 waves as 2x2; each wave 32x64 (2x4 16x16 frags), 1 MFMA per frag per K-step.
template<int K, int LDC, int GX>
__global__ __launch_bounds__(256, 4) void gemm_f16(
    const unsigned short* __restrict__ A,
    const unsigned short* __restrict__ BT,
    float* __restrict__ C) {
    __shared__ __align__(16) unsigned short lA[2][64 * 32];    // 4KB x2
    __shared__ __align__(16) unsigned short lB[2][128 * 32];   // 8KB x2 => 24KB total
    int tid = threadIdx.x;
    int lane = tid & 63;
    int w = tid >> 6;
    int wm = w >> 1, wn = w & 1;
    int r = lane & 15, g4 = lane >> 4;

    // bijective XCD swizzle (m204)
    constexpr int NWG = GX * 100;
    constexpr int Q = NWG / 8, R = NWG % 8;
    int flat = blockIdx.y * GX + blockIdx.x;
    int xcd = flat & 7, idx = flat >> 3;
    int nf = (xcd < R ? xcd * (Q + 1) : R * (Q + 1) + (xcd - R) * Q) + idx;
    int col0 = (nf % GX) * 128;
    int row0 = (nf / GX) * 64;

    f32x4 acc[2][4] = {};

    // staging: linear LDS dest; global source k-slot pre-swizzled (rule #21)
    int rS = tid >> 2;                  // staged row 0..63
    int slot = tid & 3;                 // 16B slot within row
    int tk = (slot ^ (rS & 3)) * 8;     // swizzled k offset (halves)

#define STAGE(sel, kk) do { \
    GLOAD16(A + (size_t)(row0 + rS) * K + (kk) + tk, &lA[sel][tid * 8]); \
    GLOAD16(BT + (size_t)(col0 + rS) * K + (kk) + tk, &lB[sel][tid * 8]); \
    GLOAD16(BT + (size_t)(col0 + 64 + rS) * K + (kk) + tk, &lB[sel][(tid + 256) * 8]); \
} while (0)

    STAGE(0, 0);
    asm volatile("s_waitcnt vmcnt(0)" ::: "memory");
    __syncthreads();

    constexpr int NT = K >> 5;
    int sw = (g4 ^ (r & 3)) << 3;       // swizzled read slot (halves)
    #pragma unroll 2
    for (int t = 0; t < NT; ++t) {
        int cur = t & 1;
        if (t + 1 < NT) STAGE((t + 1) & 1, (t + 1) * 32);
        half8 a[2], bf[4];
        #pragma unroll
        for (int mi = 0; mi < 2; ++mi)
            a[mi] = *(const half8*)&lA[cur][(wm * 32 + mi * 16 + r) * 32 + sw];
        #pragma unroll
        for (int ni = 0; ni < 4; ++ni)
            bf[ni] = *(const half8*)&lB[cur][(wn * 64 + ni * 16 + r) * 32 + sw];
        #pragma unroll
        for (int mi = 0; mi < 2; ++mi)
            #pragma unroll
            for (int ni = 0; ni < 4; ++ni)
                acc[mi][ni] = __builtin_amdgcn_mfma_f32_16x16x32_f16(a[mi], bf[ni], acc[mi][ni], 0, 0, 0);
        asm volatile("s_waitcnt vmcnt(0)" ::: "memory");
        __syncthreads();
    }
#undef STAGE

    #pragma unroll
    for (int mi = 0; mi < 2; ++mi) {
        #pragma unroll
        for (int ni = 0; ni < 4; ++ni) {
            int rowb = row0 + wm * 32 + mi * 16 + g4 * 4;
            int colb = col0 + wn * 64 + ni * 16 + r;
            #pragma unroll
            for (int j = 0; j < 4; ++j)
                C[(size_t)(rowb + j) * LDC + colb] = acc[mi][ni][j];
        }
    }
}

// ---------------- layer-1 epilogue -> HLh ----------------
__global__ __launch_bounds__(256) void epi1_kernel(
    const float* __restrict__ Y1, const float* __restrict__ x,
    const float* __restrict__ bg1, const float* __restrict__ bf1, const float* __restrict__ bs1,
    const float* __restrict__ lg, const float* __restrict__ lb,
    const float* __restrict__ wsk, const float* __restrict__ bsk,
    unsigned short* __restrict__ HLh) {
    int node = blockIdx.x, o = threadIdx.x;
    __shared__ float red[8];
    size_t base = (size_t)node * 768;
    float g = Y1[base + o] + bg1[o];
    float f = Y1[base + 256 + o] + bf1[o];
    float s = Y1[base + 512 + o] + bs1[o];
    float gate = 1.f / (1.f + expf(-g));
    float y = gate * f + (1.f - gate) * s;
    float sum, sq;
    block_reduce_sum2(y, y * y, red, sum, sq);
    float mean = sum * (1.f / 256.f);
    float var = sq * (1.f / 256.f) - mean * mean;
    float v = (y - mean) * rsqrtf(var + 1e-5f) * lg[o] + lb[o];
    v = fmaxf(v, 0.f);
    float x0 = x[(size_t)(node * 12 + 11) * 2];
    float x1 = x[(size_t)(node * 12 + 11) * 2 + 1];
    float res = x0 * wsk[o] + x1 * wsk[256 + o] + bsk[o];
    HLh[(size_t)node * 256 + o] = f2h(v + res);
}

// ---------------- fused GAT (fixed + adaptive) -> U ----------------
__global__ __launch_bounds__(256) void gat_kernel(
    const float* __restrict__ Y2, const float* __restrict__ ef,
    const int* __restrict__ fei, const float* __restrict__ AeS,
    const int* __restrict__ cnt, const int* __restrict__ idxs, const float* __restrict__ logv,
    unsigned short* __restrict__ Uh) {
    int tid = threadIdx.x;
    if (blockIdx.x < NODES) {
        // ---- fixed-graph GAT -> U cols [0,256)
        int node = blockIdx.x;
        int b = node / 400, n = node % 400;
        __shared__ int snd[9];
        __shared__ float sv[9][8];
        __shared__ float al[9][8];
        if (tid < 9) snd[tid] = fei[LL + n * 9 + tid];
        __syncthreads();
        if (tid < 72) {
            int j = tid / 8, h = tid % 8;
            int l = n * 9 + j;
            float e0 = ef[((size_t)b * LL + l) * 2];
            float e1 = ef[((size_t)b * LL + l) * 2 + 1];
            float ae = e0 * AeS[h] + e1 * AeS[8 + h];
            float aq = Y2[(size_t)node * 640 + 512 + h];
            float ak = Y2[((size_t)(b * 400 + snd[j])) * 640 + 520 + h];
            float s = aq + ak + ae;
            s = s > 0.f ? s : 0.2f * s;
            sv[j][h] = s;
        }
        __syncthreads();
        if (tid < 8) {
            int h = tid;
            float mx = -1e30f;
            for (int j = 0; j < 9; j++) mx = fmaxf(mx, sv[j][h]);
            float den = 0.f;
            for (int j = 0; j < 9; j++) { float e = expf(sv[j][h] - mx); al[j][h] = e; den += e; }
            den = fmaxf(den, 1e-12f);
            for (int j = 0; j < 9; j++) al[j][h] /= den;
        }
        __syncthreads();
        int h = tid >> 5, d = tid & 31;
        float acc = 0.f;
        for (int j = 0; j < 9; j++)
            acc += al[j][h] * Y2[((size_t)(b * 400 + snd[j])) * 640 + h * 32 + d];
        float e = acc > 0.f ? acc : (expf(acc) - 1.f);
        Uh[(size_t)node * 512 + tid] = f2h(e);
    } else {
        // ---- adaptive attention -> U cols [256,512)
        int node = blockIdx.x - NODES;
        int b = node / 400, n = node % 400;
        __shared__ int jidx[64];
        __shared__ float jlog[64];
        __shared__ float sc[64][8];
        __shared__ float alb[64][8];
        int c = cnt[n];
        if (tid < c) { jidx[tid] = idxs[n * 64 + tid]; jlog[tid] = logv[n * 64 + tid]; }
        __syncthreads();
        for (int e = tid; e < c * 8; e += 256) {
            int j = e / 8, h = e % 8;
            float aq = Y2[(size_t)node * 640 + 528 + h];
            float ak = Y2[((size_t)(b * 400 + jidx[j])) * 640 + 536 + h];
            float s = aq + ak;
            s = s > 0.f ? s : 0.2f * s;
            sc[j][h] = s + jlog[j];
        }
        __syncthreads();
        if (tid < 8) {
            int h = tid; float mx = -1e30f;
            for (int j = 0; j < c; j++) mx = fmaxf(mx, sc[j][h]);
            float den = 0.f;
            for (int j = 0; j < c; j++) { float e = expf(sc[j][h] - mx); alb[j][h] = e; den += e; }
            for (int j = 0; j < c; j++) alb[j][h] /= den;
        }
        __syncthreads();
        int h = tid >> 5, d = tid & 31;
        float acc = 0.f;
        for (int j = 0; j < c; j++)
            acc += alb[j][h] * Y2[((size_t)(b * 400 + jidx[j])) * 640 + 256 + h * 32 + d];
        float e = acc > 0.f ? acc : (expf(acc) - 1.f);
        Uh[(size_t)node * 512 + 256 + tid] = f2h(e);
    }
}

// ---------------- final fuse + output projection ----------------
__global__ __launch_bounds__(256) void final_kernel(
    const float* __restrict__ Y3,
    const float* __restrict__ fb1, const float* __restrict__ fb2, const float* __restrict__ fb3,
    const float* __restrict__ Wo, const float* __restrict__ bo,
    float* __restrict__ out) {
    int node = blockIdx.x, o = threadIdx.x;
    __shared__ float red[12];
    size_t base = (size_t)node * 768;
    float g = 1.f / (1.f + expf(-(Y3[base + o] + fb1[o])));
    float a2 = Y3[base + 256 + o] + fb2[o];
    float a3 = Y3[base + 512 + o] + fb3[o];
    float fused = tanhf(g * a2 + (1.f - g) * a3);
    float v0 = fused * Wo[o * 3 + 0];
    float v1 = fused * Wo[o * 3 + 1];
    float v2 = fused * Wo[o * 3 + 2];
    #pragma unroll
    for (int off = 32; off > 0; off >>= 1) {
        v0 += __shfl_xor(v0, off, 64);
        v1 += __shfl_xor(v1, off, 64);
        v2 += __shfl_xor(v2, off, 64);
    }
    int w = o >> 6, l = o & 63;
    if (l == 0) { red[w] = v0; red[4 + w] = v1; red[8 + w] = v2; }
    __syncthreads();
    if (o < 3) {
        float s = red[o * 4] + red[o * 4 + 1] + red[o * 4 + 2] + red[o * 4 + 3];
        out[(size_t)node * 3 + o] = s + bo[o];
    }
}

// ---------------- launcher ----------------
extern "C" void kernel_launch(void* const* d_in, const int* in_sizes, int n_in,
                              void* d_out, int out_size, void* d_ws, size_t ws_size,
                              hipStream_t stream) {
    const float* x   = (const float*)d_in[0];
    const float* ef  = (const float*)d_in[1];
    const int*   fei = (const int*)d_in[2];
    const float* wg0 = (const float*)d_in[3];
    const float* bg0 = (const float*)d_in[4];
    const float* wf0 = (const float*)d_in[5];
    const float* bf0 = (const float*)d_in[6];
    const float* ws0 = (const float*)d_in[7];
    const float* bs0 = (const float*)d_in[8];
    const float* ln0g = (const float*)d_in[9];
    const float* ln0b = (const float*)d_in[10];
    const float* wg1 = (const float*)d_in[11];
    const float* bg1 = (const float*)d_in[12];
    const float* wf1 = (const float*)d_in[13];
    const float* bf1 = (const float*)d_in[14];
    const float* ws1 = (const float*)d_in[15];
    const float* bs1 = (const float*)d_in[16];
    const float* ln1g = (const float*)d_in[17];
    const float* ln1b = (const float*)d_in[18];
    const float* wsk = (const float*)d_in[19];
    const float* bsk = (const float*)d_in[20];
    const float* sWq = (const float*)d_in[21];
    const float* sWk = (const float*)d_in[22];
    const float* sWv = (const float*)d_in[23];
    const float* sWe = (const float*)d_in[24];
    const float* saq = (const float*)d_in[25];
    const float* sak = (const float*)d_in[26];
    const float* sae = (const float*)d_in[27];
    const float* dWq = (const float*)d_in[28];
    const float* dWk = (const float*)d_in[29];
    const float* dWv = (const float*)d_in[30];
    const float* daq = (const float*)d_in[31];
    const float* dak = (const float*)d_in[32];
    const float* E1  = (const float*)d_in[33];
    const float* E2  = (const float*)d_in[34];
    const float* fW1 = (const float*)d_in[35];
    const float* fb1 = (const float*)d_in[36];
    const float* fW2 = (const float*)d_in[37];
    const float* fb2 = (const float*)d_in[38];
    const float* fW3 = (const float*)d_in[39];
    const float* fb3 = (const float*)d_in[40];
    const float* Wo  = (const float*)d_in[41];
    const float* bo  = (const float*)d_in[42];
    float* out = (float*)d_out;

    char* b = (char*)d_ws;
    unsigned short* Xh  = (unsigned short*)(b + 0);          // 9,830,400
    float*          Y1  = (float*)(b + 9830400);             // 19,660,800 (shared w/ Y2, Y3)
    unsigned short* HLh = (unsigned short*)(b + 29491200);   // 3,276,800
    unsigned short* Uh  = (unsigned short*)(b + 32768000);   // 6,553,600
    unsigned short* W1h = (unsigned short*)(b + 39321600);   // 1,179,648
    unsigned short* W2h = (unsigned short*)(b + 40501248);   // 327,680
    unsigned short* W3h = (unsigned short*)(b + 40828928);   // 786,432
    float*          AES = (float*)(b + 41615360);            // 64
    float*          LOGV= (float*)(b + 41615616);            // 102,400
    int*            CNT = (int*)(b + 41718016);              // 1,600
    int*            IDX = (int*)(b + 41719616);              // 102,400
    float*          Y2  = Y1;   // G2 output after Y1 consumed by epi1
    float*          Y3  = Y1;   // G3 output after Y2 consumed by gat

    // all input-only work in ONE launch
    prep_kernel<<<10981, 256, 0, stream>>>(
        wg1, wf1, ws1,
        sWv, dWv, sWq, saq, sWk, sak, dWq, daq, dWk, dak,
        fW1, fW2, fW3, sWe, sae, E1, E2,
        x, wg0, bg0, wf0, bf0, ws0, bs0, ln0g, ln0b,
        W1h, W2h, W3h, AES,
        CNT, IDX, LOGV, Xh);

    // G1: Y1 = X @ W1  (M=6400, N=768, K=768)
    gemm_f16<768, 768, 6><<<dim3(6, 100), 256, 0, stream>>>(Xh, W1h, Y1);

    epi1_kernel<<<NODES, 256, 0, stream>>>(Y1, x, bg1, bf1, bs1, ln1g, ln1b, wsk, bsk, HLh);

    // G2: Y2 = HL @ W2 (M=6400, N=640, K=256)
    gemm_f16<256, 640, 5><<<dim3(5, 100), 256, 0, stream>>>(HLh, W2h, Y2);

    // fused attention stages -> U
    gat_kernel<<<2 * NODES, 256, 0, stream>>>(Y2, ef, fei, AES, CNT, IDX, LOGV, Uh);

    // G3: Y3 = U @ W3 (M=6400, N=768, K=512)
    gemm_f16<512, 768, 6><<<dim3(6, 100), 256, 0, stream>>>(Uh, W3h, Y3);

    final_kernel<<<NODES, 256, 0, stream>>>(Y3, fb1, fb2, fb3, Wo, bo, out);
}